// Round 6
// baseline (226.611 us; speedup 1.0000x reference)
//
#include <hip/hip_runtime.h>
#include <math.h>

// GConvLSTM single step from zero state + linear head.
// H=C=0 initially => cheb_conv(H)=bh[g], F-gate irrelevant.
//   I = sigmoid(chebX_0 + bx0+bh0+bg0)
//   T = tanh   (chebX_2 + bx2+bh2+bg2)
//   C = I*T
//   O = sigmoid(chebX_3 + bx3+bh3+bg3 + wc2*C)
//   out = (O*tanh(C)) @ lin_w + lin_b
//
// R2: push->pull CSR gather (no float atomics).
// R3: hw transcendentals.
// R5: k_final lane=h restructure; 4-deep gather unroll.
// R6: deg/cnt histograms via XCD-local L2 atomics — replica indexed by
//     runtime XCC_ID (s_getreg), workgroup-scope atomicAdd stays in the
//     XCD's own L2 (no 32B/op memory-side write-through). Kernel-end
//     release flushes L2 -> k_reduce sees totals. Correct for ANY
//     block->XCD mapping since replica r is touched only by XCD r.
//     k_fill cursor stays device-scope (cross-XCD slot ordering).

#define NT 256
#define NREP 8

__device__ __forceinline__ int xcc_id() {
    unsigned v;
    asm volatile("s_getreg_b32 %0, hwreg(HW_REG_XCC_ID)" : "=s"(v));
    return (int)(v & (NREP - 1));
}

__global__ void k_deg_hist(const int* __restrict__ src, const int* __restrict__ dst,
                           const float* __restrict__ w, float* __restrict__ degR,
                           int* __restrict__ cntR, int nE, int N) {
    int e = blockIdx.x * blockDim.x + threadIdx.x;
    if (e >= nE) return;
    int r = xcc_id();
    // XCD-local L2 atomics: replica r only ever touched by XCD r.
    __hip_atomic_fetch_add(&degR[(size_t)r * N + src[e]], w[e],
                           __ATOMIC_RELAXED, __HIP_MEMORY_SCOPE_WORKGROUP);
    __hip_atomic_fetch_add(&cntR[(size_t)r * N + dst[e]], 1,
                           __ATOMIC_RELAXED, __HIP_MEMORY_SCOPE_WORKGROUP);
}

// reduce replicas: dinv[n] = rsqrt(sum deg), cnt[n] = sum cnt
__global__ void k_reduce(const float* __restrict__ degR, const int* __restrict__ cntR,
                         float* __restrict__ dinv, int* __restrict__ cnt, int N) {
    int n = blockIdx.x * blockDim.x + threadIdx.x;
    if (n >= N) return;
    float d = 0.f;
    int c = 0;
#pragma unroll
    for (int r = 0; r < NREP; ++r) {
        d += degR[(size_t)r * N + n];
        c += cntR[(size_t)r * N + n];
    }
    dinv[n] = d > 0.f ? rsqrtf(d) : 0.f;
    cnt[n] = c;
}

__global__ void k_scanA(const int* __restrict__ cnt, int* __restrict__ rowptr,
                        int* __restrict__ partials, int N) {
    __shared__ int s[NT];
    int t = threadIdx.x, i = blockIdx.x * NT + t;
    int v = (i < N) ? cnt[i] : 0;
    s[t] = v;
    __syncthreads();
    for (int off = 1; off < NT; off <<= 1) {
        int u = (t >= off) ? s[t - off] : 0;
        __syncthreads();
        s[t] += u;
        __syncthreads();
    }
    if (i < N) rowptr[i] = s[t] - v;
    if (t == NT - 1) partials[blockIdx.x] = s[t];
}

__global__ void k_scanB(int* __restrict__ partials, int nb) {
    __shared__ int s[1024];
    int t = threadIdx.x;
    int v = (t < nb) ? partials[t] : 0;
    s[t] = v;
    __syncthreads();
    for (int off = 1; off < 1024; off <<= 1) {
        int u = (t >= off) ? s[t - off] : 0;
        __syncthreads();
        s[t] += u;
        __syncthreads();
    }
    if (t < nb) partials[t] = s[t] - v;
}

__global__ void k_scanC(int* __restrict__ rowptr, const int* __restrict__ partials,
                        int* __restrict__ cursor, int N) {
    int i = blockIdx.x * NT + threadIdx.x;
    if (i >= N) return;
    int v = rowptr[i] + partials[blockIdx.x];
    rowptr[i] = v;
    cursor[i] = v;
}

__global__ void k_fill(const int* __restrict__ src, const int* __restrict__ dst,
                       const float* __restrict__ w, const float* __restrict__ dinv,
                       int* __restrict__ cursor, int2* __restrict__ entries, int nE) {
    int e = blockIdx.x * blockDim.x + threadIdx.x;
    if (e >= nE) return;
    int s = src[e], d = dst[e];
    float nv = -dinv[s] * w[e] * dinv[d];
    int pos = atomicAdd(&cursor[d], 1);  // device scope: cross-XCD slot order
    entries[pos] = make_int2(s, __float_as_int(nv));
}

__device__ __forceinline__ float4 ld4(const float* p) {
    return *reinterpret_cast<const float4*>(p);
}
__device__ __forceinline__ void fma4s(float4& a, float s, const float4& v) {
    a.x = fmaf(s, v.x, a.x); a.y = fmaf(s, v.y, a.y);
    a.z = fmaf(s, v.z, a.z); a.w = fmaf(s, v.w, a.w);
}

// Tx[n][f4] = scale * sum_e norm_e * t[src_e][f4] - sub[n][f4]; 8 threads/node.
__global__ __launch_bounds__(256)
void k_gather(const float* __restrict__ t, const float* __restrict__ sub,
              float* __restrict__ out, const int* __restrict__ rowptr,
              const int* __restrict__ cnt, const int2* __restrict__ entries,
              float scale, int N) {
    int idx = blockIdx.x * blockDim.x + threadIdx.x;
    if (idx >= N * 8) return;
    int n = idx >> 3, q = idx & 7;
    int beg = rowptr[n], end = beg + cnt[n];
    float4 acc0 = make_float4(0, 0, 0, 0), acc1 = make_float4(0, 0, 0, 0);
    float4 acc2 = make_float4(0, 0, 0, 0), acc3 = make_float4(0, 0, 0, 0);
    int i = beg;
    for (; i + 3 < end; i += 4) {
        int2 e0 = entries[i];
        int2 e1 = entries[i + 1];
        int2 e2 = entries[i + 2];
        int2 e3 = entries[i + 3];
        float4 v0 = ld4(t + (size_t)e0.x * 32 + q * 4);
        float4 v1 = ld4(t + (size_t)e1.x * 32 + q * 4);
        float4 v2 = ld4(t + (size_t)e2.x * 32 + q * 4);
        float4 v3 = ld4(t + (size_t)e3.x * 32 + q * 4);
        fma4s(acc0, __int_as_float(e0.y), v0);
        fma4s(acc1, __int_as_float(e1.y), v1);
        fma4s(acc2, __int_as_float(e2.y), v2);
        fma4s(acc3, __int_as_float(e3.y), v3);
    }
    for (; i < end; ++i) {
        int2 e0 = entries[i];
        fma4s(acc0, __int_as_float(e0.y), ld4(t + (size_t)e0.x * 32 + q * 4));
    }
    acc0.x += acc1.x + acc2.x + acc3.x;
    acc0.y += acc1.y + acc2.y + acc3.y;
    acc0.z += acc1.z + acc2.z + acc3.z;
    acc0.w += acc1.w + acc2.w + acc3.w;
    float4 r = make_float4(scale * acc0.x, scale * acc0.y, scale * acc0.z, scale * acc0.w);
    if (sub) {
        float4 s4 = ld4(sub + (size_t)n * 32 + q * 4);
        r.x -= s4.x; r.y -= s4.y; r.z -= s4.z; r.w -= s4.w;
    }
    *reinterpret_cast<float4*>(out + (size_t)n * 32 + q * 4) = r;
}

// pre-pack gate weights: P[((k4*3+g)*64+h)*4 + kk] = Wgate[(k4*4+kk)*64 + h]
__global__ void k_prepack(const float* __restrict__ Wx, float* __restrict__ P) {
    int idx = blockIdx.x * blockDim.x + threadIdx.x;
    if (idx >= 32 * 3 * 64) return;
    int h = idx & 63;
    int g = (idx >> 6) % 3;
    int k4 = idx / 192;
    const int gate = (g == 0) ? 0 : (g == 1) ? 2 : 3;
    const float* W = Wx + gate * 8192;
    float4 v;
    v.x = W[(k4 * 4 + 0) * 64 + h];
    v.y = W[(k4 * 4 + 1) * 64 + h];
    v.z = W[(k4 * 4 + 2) * 64 + h];
    v.w = W[(k4 * 4 + 3) * 64 + h];
    *reinterpret_cast<float4*>(P + (size_t)idx * 4) = v;
}

__device__ __forceinline__ float sigf(float x) {
    return __builtin_amdgcn_rcpf(1.f + __builtin_amdgcn_exp2f(-1.4426950408889634f * x));
}
__device__ __forceinline__ float tanhf_fast(float x) {
    float e = __builtin_amdgcn_exp2f(2.8853900817779268f * x);
    return 1.f - 2.f * __builtin_amdgcn_rcpf(e + 1.f);
}
__device__ __forceinline__ float dot4(float4 a, float4 b, float acc) {
    return fmaf(a.x, b.x, fmaf(a.y, b.y, fmaf(a.z, b.z, fmaf(a.w, b.w, acc))));
}

// Fused gates GEMM + LSTM pointwise + linear head. lane = h.
__global__ __launch_bounds__(256)
void k_final(const float* __restrict__ tx0, const float* __restrict__ tx1,
             const float* __restrict__ tx2, const float* __restrict__ tx3,
             const float* __restrict__ P, const float* __restrict__ bx,
             const float* __restrict__ bh, const float* __restrict__ wc,
             const float* __restrict__ bg, const float* __restrict__ lin_w,
             const float* __restrict__ lin_b, float* __restrict__ out, int N) {
    __shared__ float rows[32][128];
    const int tid = threadIdx.x;
    const int base = blockIdx.x * 32;

    for (int i = tid; i < 32 * 32; i += 256) {
        int nl = i >> 5, f4 = i & 31;
        int n = base + nl;
        float4 v = make_float4(0, 0, 0, 0);
        if (n < N) {
            int f5 = f4 >> 3;
            const float* bp = (f5 == 0) ? tx0 : (f5 == 1) ? tx1 : (f5 == 2) ? tx2 : tx3;
            v = ld4(bp + (size_t)n * 32 + (f4 & 7) * 4);
        }
        *reinterpret_cast<float4*>(&rows[nl][f4 * 4]) = v;
    }
    __syncthreads();

    const int wave = tid >> 6, lane = tid & 63;
    const int nrow = wave * 8;

    float accI[8], accC[8], accO[8];
#pragma unroll
    for (int j = 0; j < 8; ++j) { accI[j] = 0.f; accC[j] = 0.f; accO[j] = 0.f; }

    for (int k4 = 0; k4 < 32; ++k4) {
        const float* Pb = P + (size_t)k4 * 768 + lane * 4;
        float4 wi  = ld4(Pb);
        float4 wcg = ld4(Pb + 256);
        float4 wog = ld4(Pb + 512);
#pragma unroll
        for (int j = 0; j < 8; ++j) {
            float4 tq = ld4(&rows[nrow + j][k4 * 4]);
            accI[j] = dot4(tq, wi,  accI[j]);
            accC[j] = dot4(tq, wcg, accC[j]);
            accO[j] = dot4(tq, wog, accO[j]);
        }
    }

    const float bI = bx[lane] + bh[lane] + bg[lane];
    const float bC = bx[128 + lane] + bh[128 + lane] + bg[128 + lane];
    const float bO = bx[192 + lane] + bh[192 + lane] + bg[192 + lane];
    const float wc2s = wc[128 + lane];
    const float lws = lin_w[lane];
    const float lb = lin_b[0];

#pragma unroll
    for (int j = 0; j < 8; ++j) {
        float I = sigf(accI[j] + bI);
        float T = tanhf_fast(accC[j] + bC);
        float C = I * T;
        float O = sigf(accO[j] + bO + wc2s * C);
        float H = O * tanhf_fast(C);

        float p = H * lws;
        p += __shfl_xor(p, 1);
        p += __shfl_xor(p, 2);
        p += __shfl_xor(p, 4);
        p += __shfl_xor(p, 8);
        p += __shfl_xor(p, 16);
        p += __shfl_xor(p, 32);
        int n = base + nrow + j;
        if (lane == 0 && n < N) out[n] = p + lb;
    }
}

extern "C" void kernel_launch(void* const* d_in, const int* in_sizes, int n_in,
                              void* d_out, int out_size, void* d_ws, size_t ws_size,
                              hipStream_t stream) {
    const float* x   = (const float*)d_in[0];
    const int*   ei  = (const int*)d_in[1];
    const float* ew  = (const float*)d_in[2];
    const float* Wx  = (const float*)d_in[3];
    const float* bx  = (const float*)d_in[4];
    // d_in[5] = Wh (unused: zero initial state)
    const float* bh  = (const float*)d_in[6];
    const float* wcp = (const float*)d_in[7];
    const float* bg  = (const float*)d_in[8];
    const float* lw  = (const float*)d_in[9];
    const float* lb  = (const float*)d_in[10];
    float* out = (float*)d_out;

    const int N  = in_sizes[0] / 32;
    const int nE = in_sizes[2];
    const int* src = ei;
    const int* dst = ei + nE;

    char* ws = (char*)d_ws;
    size_t off = 0;
    float* dinv    = (float*)(ws + off); off += (size_t)N * 4;
    int*   cnt     = (int*)(ws + off);   off += (size_t)N * 4;
    int*   rowptr  = (int*)(ws + off);   off += (size_t)N * 4;
    int*   cursor  = (int*)(ws + off);   off += (size_t)N * 4;
    int*   partials= (int*)(ws + off);   off += 1024 * 4;
    float* P       = (float*)(ws + off); off += 32 * 3 * 64 * 4 * 4;
    int2*  entries = (int2*)(ws + off);  off += (size_t)nE * 8;
    float* Tx1     = (float*)(ws + off); off += (size_t)N * 32 * 4;
    float* Tx2     = (float*)(ws + off); off += (size_t)N * 32 * 4;
    float* Tx3     = (float*)(ws + off); off += (size_t)N * 32 * 4;

    // replicas alias Tx1/Tx2 (dead before gathers overwrite them)
    float* degR = Tx1;          // NREP * N floats
    int*   cntR = (int*)Tx2;    // NREP * N ints

    hipMemsetAsync(degR, 0, (size_t)NREP * N * 4, stream);
    hipMemsetAsync(cntR, 0, (size_t)NREP * N * 4, stream);

    const int eb = (nE + NT - 1) / NT;
    const int nb = (N + NT - 1) / NT;

    k_deg_hist<<<eb, NT, 0, stream>>>(src, dst, ew, degR, cntR, nE, N);
    k_prepack<<<(32 * 3 * 64 + NT - 1) / NT, NT, 0, stream>>>(Wx, P);
    k_reduce<<<nb, NT, 0, stream>>>(degR, cntR, dinv, cnt, N);
    k_scanA<<<nb, NT, 0, stream>>>(cnt, rowptr, partials, N);
    k_scanB<<<1, 1024, 0, stream>>>(partials, nb);
    k_scanC<<<nb, NT, 0, stream>>>(rowptr, partials, cursor, N);
    k_fill<<<eb, NT, 0, stream>>>(src, dst, ew, dinv, cursor, entries, nE);

    const int gb = (N * 8 + NT - 1) / NT;
    k_gather<<<gb, NT, 0, stream>>>(x,   nullptr, Tx1, rowptr, cnt, entries, 1.f, N);
    k_gather<<<gb, NT, 0, stream>>>(Tx1, x,       Tx2, rowptr, cnt, entries, 2.f, N);
    k_gather<<<gb, NT, 0, stream>>>(Tx2, Tx1,     Tx3, rowptr, cnt, entries, 2.f, N);

    const int fb = (N + 31) / 32;
    k_final<<<fb, NT, 0, stream>>>(x, Tx1, Tx2, Tx3, P, bx, bh, wcp, bg,
                                   lw, lb, out, N);
}

// Round 7
// 173.307 us; speedup vs baseline: 1.3076x; 1.3076x over previous
//
#include <hip/hip_runtime.h>
#include <math.h>

// GConvLSTM single step from zero state + linear head.
// H=C=0 initially => cheb_conv(H)=bh[g], F-gate irrelevant.
//   I = sigmoid(chebX_0 + bx0+bh0+bg0)
//   T = tanh   (chebX_2 + bx2+bh2+bg2)
//   C = I*T
//   O = sigmoid(chebX_3 + bx3+bh3+bg3 + wc2*C)
//   out = (O*tanh(C)) @ lin_w + lin_b
//
// R2: push->pull CSR gather.  R3: hw transcendentals.
// R5: k_final lane=h; 4-deep gather unroll.
// R7: ZERO global atomics. R6 showed gfx950 global atomics execute at the
//     memory-side coherence point (32B write-through each, ~23 G/s) and
//     scope hints don't change that. Replace with range-partitioned LDS
//     histograms (k_hist) + per-chunk offset scan (k_scan_off) + LDS-cursor
//     counting-sort fill (k_fill2). Edge list (9.6MB) is L3-resident across
//     the 7 range passes.

#define NT 256
#define RS 8192     // nodes per range (LDS histogram size)
#define NCH 32      // edge chunks

// per-(range, chunk) LDS histogram of deg(by src) and cnt(by dst);
// non-atomic flush to per-chunk partials.
__global__ __launch_bounds__(1024)
void k_hist(const int* __restrict__ src, const int* __restrict__ dst,
            const float* __restrict__ w, float* __restrict__ degPart,
            int* __restrict__ cntPart, int nE, int N) {
    __shared__ float s_deg[RS];
    __shared__ int   s_cnt[RS];
    const int r = blockIdx.x / NCH, b = blockIdx.x % NCH;
    const int base = r * RS;
    for (int i = threadIdx.x; i < RS; i += 1024) { s_deg[i] = 0.f; s_cnt[i] = 0; }
    __syncthreads();
    const int chunk = (nE + NCH - 1) / NCH;
    const int e0 = b * chunk, e1 = min(e0 + chunk, nE);
    for (int e = e0 + (int)threadIdx.x; e < e1; e += 1024) {
        int s = src[e], d = dst[e];
        unsigned so = (unsigned)(s - base), dof = (unsigned)(d - base);
        if (so < RS) atomicAdd(&s_deg[so], w[e]);
        if (dof < RS) atomicAdd(&s_cnt[dof], 1);
    }
    __syncthreads();
    for (int i = threadIdx.x; i < RS; i += 1024) {
        int n = base + i;
        if (n < N) {
            degPart[(size_t)b * N + n] = s_deg[i];
            cntPart[(size_t)b * N + n] = s_cnt[i];
        }
    }
}

// reduce partials: dinv[n] = rsqrt(sum deg), cnt[n] = sum cnt
__global__ void k_reduce(const float* __restrict__ degPart, const int* __restrict__ cntPart,
                         float* __restrict__ dinv, int* __restrict__ cnt, int N) {
    int n = blockIdx.x * blockDim.x + threadIdx.x;
    if (n >= N) return;
    float d = 0.f;
    int c = 0;
#pragma unroll
    for (int b = 0; b < NCH; ++b) {
        d += degPart[(size_t)b * N + n];
        c += cntPart[(size_t)b * N + n];
    }
    dinv[n] = d > 0.f ? rsqrtf(d) : 0.f;
    cnt[n] = c;
}

__global__ void k_scanA(const int* __restrict__ cnt, int* __restrict__ rowptr,
                        int* __restrict__ partials, int N) {
    __shared__ int s[NT];
    int t = threadIdx.x, i = blockIdx.x * NT + t;
    int v = (i < N) ? cnt[i] : 0;
    s[t] = v;
    __syncthreads();
    for (int off = 1; off < NT; off <<= 1) {
        int u = (t >= off) ? s[t - off] : 0;
        __syncthreads();
        s[t] += u;
        __syncthreads();
    }
    if (i < N) rowptr[i] = s[t] - v;
    if (t == NT - 1) partials[blockIdx.x] = s[t];
}

__global__ void k_scanB(int* __restrict__ partials, int nb) {
    __shared__ int s[1024];
    int t = threadIdx.x;
    int v = (t < nb) ? partials[t] : 0;
    s[t] = v;
    __syncthreads();
    for (int off = 1; off < 1024; off <<= 1) {
        int u = (t >= off) ? s[t - off] : 0;
        __syncthreads();
        s[t] += u;
        __syncthreads();
    }
    if (t < nb) partials[t] = s[t] - v;
}

__global__ void k_scanC(int* __restrict__ rowptr, const int* __restrict__ partials, int N) {
    int i = blockIdx.x * NT + threadIdx.x;
    if (i >= N) return;
    rowptr[i] += partials[blockIdx.x];
}

// exclusive scan over chunk axis: cntPart[b][n] <- rowptr[n] + sum_{b'<b} cnt
__global__ void k_scan_off(int* __restrict__ cntPart, const int* __restrict__ rowptr, int N) {
    int n = blockIdx.x * blockDim.x + threadIdx.x;
    if (n >= N) return;
    int s = rowptr[n];
#pragma unroll
    for (int b = 0; b < NCH; ++b) {
        int t = cntPart[(size_t)b * N + n];
        cntPart[(size_t)b * N + n] = s;
        s += t;
    }
}

// counting-sort fill: LDS cursor seeded from per-chunk offsets, LDS-atomic
// rank, plain global store. Zero global atomics.
__global__ __launch_bounds__(1024)
void k_fill2(const int* __restrict__ src, const int* __restrict__ dst,
             const float* __restrict__ w, const float* __restrict__ dinv,
             const int* __restrict__ offs, int2* __restrict__ entries,
             int nE, int N) {
    __shared__ int s_cur[RS];
    const int r = blockIdx.x / NCH, b = blockIdx.x % NCH;
    const int base = r * RS;
    for (int i = threadIdx.x; i < RS; i += 1024) {
        int n = base + i;
        s_cur[i] = (n < N) ? offs[(size_t)b * N + n] : 0;
    }
    __syncthreads();
    const int chunk = (nE + NCH - 1) / NCH;
    const int e0 = b * chunk, e1 = min(e0 + chunk, nE);
    for (int e = e0 + (int)threadIdx.x; e < e1; e += 1024) {
        int d = dst[e];
        unsigned dof = (unsigned)(d - base);
        if (dof < RS) {
            int s = src[e];
            float nv = -dinv[s] * w[e] * dinv[d];
            int pos = atomicAdd(&s_cur[dof], 1);
            entries[pos] = make_int2(s, __float_as_int(nv));
        }
    }
}

__device__ __forceinline__ float4 ld4(const float* p) {
    return *reinterpret_cast<const float4*>(p);
}
__device__ __forceinline__ void fma4s(float4& a, float s, const float4& v) {
    a.x = fmaf(s, v.x, a.x); a.y = fmaf(s, v.y, a.y);
    a.z = fmaf(s, v.z, a.z); a.w = fmaf(s, v.w, a.w);
}

// Tx[n][f4] = scale * sum_e norm_e * t[src_e][f4] - sub[n][f4]; 8 threads/node.
__global__ __launch_bounds__(256)
void k_gather(const float* __restrict__ t, const float* __restrict__ sub,
              float* __restrict__ out, const int* __restrict__ rowptr,
              const int* __restrict__ cnt, const int2* __restrict__ entries,
              float scale, int N) {
    int idx = blockIdx.x * blockDim.x + threadIdx.x;
    if (idx >= N * 8) return;
    int n = idx >> 3, q = idx & 7;
    int beg = rowptr[n], end = beg + cnt[n];
    float4 acc0 = make_float4(0, 0, 0, 0), acc1 = make_float4(0, 0, 0, 0);
    float4 acc2 = make_float4(0, 0, 0, 0), acc3 = make_float4(0, 0, 0, 0);
    int i = beg;
    for (; i + 3 < end; i += 4) {
        int2 e0 = entries[i];
        int2 e1 = entries[i + 1];
        int2 e2 = entries[i + 2];
        int2 e3 = entries[i + 3];
        float4 v0 = ld4(t + (size_t)e0.x * 32 + q * 4);
        float4 v1 = ld4(t + (size_t)e1.x * 32 + q * 4);
        float4 v2 = ld4(t + (size_t)e2.x * 32 + q * 4);
        float4 v3 = ld4(t + (size_t)e3.x * 32 + q * 4);
        fma4s(acc0, __int_as_float(e0.y), v0);
        fma4s(acc1, __int_as_float(e1.y), v1);
        fma4s(acc2, __int_as_float(e2.y), v2);
        fma4s(acc3, __int_as_float(e3.y), v3);
    }
    for (; i < end; ++i) {
        int2 e0 = entries[i];
        fma4s(acc0, __int_as_float(e0.y), ld4(t + (size_t)e0.x * 32 + q * 4));
    }
    acc0.x += acc1.x + acc2.x + acc3.x;
    acc0.y += acc1.y + acc2.y + acc3.y;
    acc0.z += acc1.z + acc2.z + acc3.z;
    acc0.w += acc1.w + acc2.w + acc3.w;
    float4 r = make_float4(scale * acc0.x, scale * acc0.y, scale * acc0.z, scale * acc0.w);
    if (sub) {
        float4 s4 = ld4(sub + (size_t)n * 32 + q * 4);
        r.x -= s4.x; r.y -= s4.y; r.z -= s4.z; r.w -= s4.w;
    }
    *reinterpret_cast<float4*>(out + (size_t)n * 32 + q * 4) = r;
}

// pre-pack gate weights: P[((k4*3+g)*64+h)*4 + kk] = Wgate[(k4*4+kk)*64 + h]
__global__ void k_prepack(const float* __restrict__ Wx, float* __restrict__ P) {
    int idx = blockIdx.x * blockDim.x + threadIdx.x;
    if (idx >= 32 * 3 * 64) return;
    int h = idx & 63;
    int g = (idx >> 6) % 3;
    int k4 = idx / 192;
    const int gate = (g == 0) ? 0 : (g == 1) ? 2 : 3;
    const float* W = Wx + gate * 8192;
    float4 v;
    v.x = W[(k4 * 4 + 0) * 64 + h];
    v.y = W[(k4 * 4 + 1) * 64 + h];
    v.z = W[(k4 * 4 + 2) * 64 + h];
    v.w = W[(k4 * 4 + 3) * 64 + h];
    *reinterpret_cast<float4*>(P + (size_t)idx * 4) = v;
}

__device__ __forceinline__ float sigf(float x) {
    return __builtin_amdgcn_rcpf(1.f + __builtin_amdgcn_exp2f(-1.4426950408889634f * x));
}
__device__ __forceinline__ float tanhf_fast(float x) {
    float e = __builtin_amdgcn_exp2f(2.8853900817779268f * x);
    return 1.f - 2.f * __builtin_amdgcn_rcpf(e + 1.f);
}
__device__ __forceinline__ float dot4(float4 a, float4 b, float acc) {
    return fmaf(a.x, b.x, fmaf(a.y, b.y, fmaf(a.z, b.z, fmaf(a.w, b.w, acc))));
}

// Fused gates GEMM + LSTM pointwise + linear head. lane = h.
__global__ __launch_bounds__(256)
void k_final(const float* __restrict__ tx0, const float* __restrict__ tx1,
             const float* __restrict__ tx2, const float* __restrict__ tx3,
             const float* __restrict__ P, const float* __restrict__ bx,
             const float* __restrict__ bh, const float* __restrict__ wc,
             const float* __restrict__ bg, const float* __restrict__ lin_w,
             const float* __restrict__ lin_b, float* __restrict__ out, int N) {
    __shared__ float rows[32][128];
    const int tid = threadIdx.x;
    const int base = blockIdx.x * 32;

    for (int i = tid; i < 32 * 32; i += 256) {
        int nl = i >> 5, f4 = i & 31;
        int n = base + nl;
        float4 v = make_float4(0, 0, 0, 0);
        if (n < N) {
            int f5 = f4 >> 3;
            const float* bp = (f5 == 0) ? tx0 : (f5 == 1) ? tx1 : (f5 == 2) ? tx2 : tx3;
            v = ld4(bp + (size_t)n * 32 + (f4 & 7) * 4);
        }
        *reinterpret_cast<float4*>(&rows[nl][f4 * 4]) = v;
    }
    __syncthreads();

    const int wave = tid >> 6, lane = tid & 63;
    const int nrow = wave * 8;

    float accI[8], accC[8], accO[8];
#pragma unroll
    for (int j = 0; j < 8; ++j) { accI[j] = 0.f; accC[j] = 0.f; accO[j] = 0.f; }

    for (int k4 = 0; k4 < 32; ++k4) {
        const float* Pb = P + (size_t)k4 * 768 + lane * 4;
        float4 wi  = ld4(Pb);
        float4 wcg = ld4(Pb + 256);
        float4 wog = ld4(Pb + 512);
#pragma unroll
        for (int j = 0; j < 8; ++j) {
            float4 tq = ld4(&rows[nrow + j][k4 * 4]);
            accI[j] = dot4(tq, wi,  accI[j]);
            accC[j] = dot4(tq, wcg, accC[j]);
            accO[j] = dot4(tq, wog, accO[j]);
        }
    }

    const float bI = bx[lane] + bh[lane] + bg[lane];
    const float bC = bx[128 + lane] + bh[128 + lane] + bg[128 + lane];
    const float bO = bx[192 + lane] + bh[192 + lane] + bg[192 + lane];
    const float wc2s = wc[128 + lane];
    const float lws = lin_w[lane];
    const float lb = lin_b[0];

#pragma unroll
    for (int j = 0; j < 8; ++j) {
        float I = sigf(accI[j] + bI);
        float T = tanhf_fast(accC[j] + bC);
        float C = I * T;
        float O = sigf(accO[j] + bO + wc2s * C);
        float H = O * tanhf_fast(C);

        float p = H * lws;
        p += __shfl_xor(p, 1);
        p += __shfl_xor(p, 2);
        p += __shfl_xor(p, 4);
        p += __shfl_xor(p, 8);
        p += __shfl_xor(p, 16);
        p += __shfl_xor(p, 32);
        int n = base + nrow + j;
        if (lane == 0 && n < N) out[n] = p + lb;
    }
}

extern "C" void kernel_launch(void* const* d_in, const int* in_sizes, int n_in,
                              void* d_out, int out_size, void* d_ws, size_t ws_size,
                              hipStream_t stream) {
    const float* x   = (const float*)d_in[0];
    const int*   ei  = (const int*)d_in[1];
    const float* ew  = (const float*)d_in[2];
    const float* Wx  = (const float*)d_in[3];
    const float* bx  = (const float*)d_in[4];
    // d_in[5] = Wh (unused: zero initial state)
    const float* bh  = (const float*)d_in[6];
    const float* wcp = (const float*)d_in[7];
    const float* bg  = (const float*)d_in[8];
    const float* lw  = (const float*)d_in[9];
    const float* lb  = (const float*)d_in[10];
    float* out = (float*)d_out;

    const int N  = in_sizes[0] / 32;
    const int nE = in_sizes[2];
    const int* src = ei;
    const int* dst = ei + nE;

    char* ws = (char*)d_ws;
    size_t off = 0;
    float* dinv    = (float*)(ws + off); off += (size_t)N * 4;
    int*   cnt     = (int*)(ws + off);   off += (size_t)N * 4;
    int*   rowptr  = (int*)(ws + off);   off += (size_t)N * 4;
    int*   partials= (int*)(ws + off);   off += 1024 * 4;
    float* P       = (float*)(ws + off); off += 32 * 3 * 64 * 4 * 4;
    int2*  entries = (int2*)(ws + off);  off += (size_t)nE * 8;
    float* Tx1     = (float*)(ws + off); off += (size_t)N * 32 * 4;
    float* Tx2     = (float*)(ws + off); off += (size_t)N * 32 * 4;
    float* Tx3     = (float*)(ws + off); off += (size_t)N * 32 * 4;

    // partials alias Tx1/Tx2 (dead until gathers): NCH*N floats/ints each
    float* degPart = Tx1;
    int*   cntPart = (int*)Tx2;

    const int nb = (N + NT - 1) / NT;
    const int nRange = (N + RS - 1) / RS;

    k_hist<<<nRange * NCH, 1024, 0, stream>>>(src, dst, ew, degPart, cntPart, nE, N);
    k_prepack<<<(32 * 3 * 64 + NT - 1) / NT, NT, 0, stream>>>(Wx, P);
    k_reduce<<<nb, NT, 0, stream>>>(degPart, cntPart, dinv, cnt, N);
    k_scanA<<<nb, NT, 0, stream>>>(cnt, rowptr, partials, N);
    k_scanB<<<1, 1024, 0, stream>>>(partials, nb);
    k_scanC<<<nb, NT, 0, stream>>>(rowptr, partials, N);
    k_scan_off<<<nb, NT, 0, stream>>>(cntPart, rowptr, N);
    k_fill2<<<nRange * NCH, 1024, 0, stream>>>(src, dst, ew, dinv, cntPart,
                                               entries, nE, N);

    const int gb = (N * 8 + NT - 1) / NT;
    k_gather<<<gb, NT, 0, stream>>>(x,   nullptr, Tx1, rowptr, cnt, entries, 1.f, N);
    k_gather<<<gb, NT, 0, stream>>>(Tx1, x,       Tx2, rowptr, cnt, entries, 2.f, N);
    k_gather<<<gb, NT, 0, stream>>>(Tx2, Tx1,     Tx3, rowptr, cnt, entries, 2.f, N);

    const int fb = (N + 31) / 32;
    k_final<<<fb, NT, 0, stream>>>(x, Tx1, Tx2, Tx3, P, bx, bh, wcp, bg,
                                   lw, lb, out, N);
}

// Round 8
// 145.198 us; speedup vs baseline: 1.5607x; 1.1936x over previous
//
#include <hip/hip_runtime.h>
#include <math.h>

// GConvLSTM single step from zero state + linear head.
// H=C=0 initially => cheb_conv(H)=bh[g], F-gate irrelevant.
//   I = sigmoid(chebX_0 + bx0+bh0+bg0)
//   T = tanh   (chebX_2 + bx2+bh2+bg2)
//   C = I*T
//   O = sigmoid(chebX_3 + bx3+bh3+bg3 + wc2*C)
//   out = (O*tanh(C)) @ lin_w + lin_b
//
// R2: push->pull CSR gather.  R3: hw transcendentals.
// R7: zero global atomics (LDS histograms + counting-sort fill).
// R8: k_final via bf16 MFMA (mfma_f32_16x16x32_bf16). Chebyshev recursion
//     stays fp32; only k_final operands are bf16 (Tx bf16 copies fused into
//     gather epilogue; W prepacked into B-fragments). Layouts per verified
//     m89/m91: A row=lane&15, k=(lane>>4)*8+j; B col=lane&15 same k;
//     D col=lane&15, row=(lane>>4)*4+reg.

#define NT 256
#define RS 8192     // nodes per range (LDS histogram size)
#define NCH 32      // edge chunks

typedef __attribute__((ext_vector_type(8))) short short8v;
typedef __attribute__((ext_vector_type(4))) float f32x4;

__device__ __forceinline__ short f2bf(float f) {
    unsigned u = __float_as_uint(f);
    u += 0x7FFFu + ((u >> 16) & 1u);   // round-to-nearest-even
    return (short)(u >> 16);
}

// per-(range, chunk) LDS histogram of deg(by src) and cnt(by dst);
// non-atomic flush to per-chunk partials.
__global__ __launch_bounds__(1024)
void k_hist(const int* __restrict__ src, const int* __restrict__ dst,
            const float* __restrict__ w, float* __restrict__ degPart,
            int* __restrict__ cntPart, int nE, int N) {
    __shared__ float s_deg[RS];
    __shared__ int   s_cnt[RS];
    const int r = blockIdx.x / NCH, b = blockIdx.x % NCH;
    const int base = r * RS;
    for (int i = threadIdx.x; i < RS; i += 1024) { s_deg[i] = 0.f; s_cnt[i] = 0; }
    __syncthreads();
    const int chunk = (nE + NCH - 1) / NCH;
    const int e0 = b * chunk, e1 = min(e0 + chunk, nE);
    for (int e = e0 + (int)threadIdx.x; e < e1; e += 1024) {
        int s = src[e], d = dst[e];
        unsigned so = (unsigned)(s - base), dof = (unsigned)(d - base);
        if (so < RS) atomicAdd(&s_deg[so], w[e]);
        if (dof < RS) atomicAdd(&s_cnt[dof], 1);
    }
    __syncthreads();
    for (int i = threadIdx.x; i < RS; i += 1024) {
        int n = base + i;
        if (n < N) {
            degPart[(size_t)b * N + n] = s_deg[i];
            cntPart[(size_t)b * N + n] = s_cnt[i];
        }
    }
}

__global__ void k_reduce(const float* __restrict__ degPart, const int* __restrict__ cntPart,
                         float* __restrict__ dinv, int* __restrict__ cnt, int N) {
    int n = blockIdx.x * blockDim.x + threadIdx.x;
    if (n >= N) return;
    float d = 0.f;
    int c = 0;
#pragma unroll
    for (int b = 0; b < NCH; ++b) {
        d += degPart[(size_t)b * N + n];
        c += cntPart[(size_t)b * N + n];
    }
    dinv[n] = d > 0.f ? rsqrtf(d) : 0.f;
    cnt[n] = c;
}

__global__ void k_scanA(const int* __restrict__ cnt, int* __restrict__ rowptr,
                        int* __restrict__ partials, int N) {
    __shared__ int s[NT];
    int t = threadIdx.x, i = blockIdx.x * NT + t;
    int v = (i < N) ? cnt[i] : 0;
    s[t] = v;
    __syncthreads();
    for (int off = 1; off < NT; off <<= 1) {
        int u = (t >= off) ? s[t - off] : 0;
        __syncthreads();
        s[t] += u;
        __syncthreads();
    }
    if (i < N) rowptr[i] = s[t] - v;
    if (t == NT - 1) partials[blockIdx.x] = s[t];
}

__global__ void k_scanB(int* __restrict__ partials, int nb) {
    __shared__ int s[1024];
    int t = threadIdx.x;
    int v = (t < nb) ? partials[t] : 0;
    s[t] = v;
    __syncthreads();
    for (int off = 1; off < 1024; off <<= 1) {
        int u = (t >= off) ? s[t - off] : 0;
        __syncthreads();
        s[t] += u;
        __syncthreads();
    }
    if (t < nb) partials[t] = s[t] - v;
}

__global__ void k_scanC(int* __restrict__ rowptr, const int* __restrict__ partials, int N) {
    int i = blockIdx.x * NT + threadIdx.x;
    if (i >= N) return;
    rowptr[i] += partials[blockIdx.x];
}

__global__ void k_scan_off(int* __restrict__ cntPart, const int* __restrict__ rowptr, int N) {
    int n = blockIdx.x * blockDim.x + threadIdx.x;
    if (n >= N) return;
    int s = rowptr[n];
#pragma unroll
    for (int b = 0; b < NCH; ++b) {
        int t = cntPart[(size_t)b * N + n];
        cntPart[(size_t)b * N + n] = s;
        s += t;
    }
}

__global__ __launch_bounds__(1024)
void k_fill2(const int* __restrict__ src, const int* __restrict__ dst,
             const float* __restrict__ w, const float* __restrict__ dinv,
             const int* __restrict__ offs, int2* __restrict__ entries,
             int nE, int N) {
    __shared__ int s_cur[RS];
    const int r = blockIdx.x / NCH, b = blockIdx.x % NCH;
    const int base = r * RS;
    for (int i = threadIdx.x; i < RS; i += 1024) {
        int n = base + i;
        s_cur[i] = (n < N) ? offs[(size_t)b * N + n] : 0;
    }
    __syncthreads();
    const int chunk = (nE + NCH - 1) / NCH;
    const int e0 = b * chunk, e1 = min(e0 + chunk, nE);
    for (int e = e0 + (int)threadIdx.x; e < e1; e += 1024) {
        int d = dst[e];
        unsigned dof = (unsigned)(d - base);
        if (dof < RS) {
            int s = src[e];
            float nv = -dinv[s] * w[e] * dinv[d];
            int pos = atomicAdd(&s_cur[dof], 1);
            entries[pos] = make_int2(s, __float_as_int(nv));
        }
    }
}

__device__ __forceinline__ float4 ld4(const float* p) {
    return *reinterpret_cast<const float4*>(p);
}
__device__ __forceinline__ void fma4s(float4& a, float s, const float4& v) {
    a.x = fmaf(s, v.x, a.x); a.y = fmaf(s, v.y, a.y);
    a.z = fmaf(s, v.z, a.z); a.w = fmaf(s, v.w, a.w);
}

// Tx[n][f4] = scale * sum_e norm_e * t[src_e][f4] - sub[n][f4]; 8 threads/node.
// f32 recursion output (optional) + bf16 copy for k_final.
__global__ __launch_bounds__(256)
void k_gather(const float* __restrict__ t, const float* __restrict__ sub,
              float* __restrict__ outf, short* __restrict__ outb,
              const int* __restrict__ rowptr, const int* __restrict__ cnt,
              const int2* __restrict__ entries, float scale, int N) {
    int idx = blockIdx.x * blockDim.x + threadIdx.x;
    if (idx >= N * 8) return;
    int n = idx >> 3, q = idx & 7;
    int beg = rowptr[n], end = beg + cnt[n];
    float4 acc0 = make_float4(0, 0, 0, 0), acc1 = make_float4(0, 0, 0, 0);
    float4 acc2 = make_float4(0, 0, 0, 0), acc3 = make_float4(0, 0, 0, 0);
    int i = beg;
    for (; i + 3 < end; i += 4) {
        int2 e0 = entries[i];
        int2 e1 = entries[i + 1];
        int2 e2 = entries[i + 2];
        int2 e3 = entries[i + 3];
        float4 v0 = ld4(t + (size_t)e0.x * 32 + q * 4);
        float4 v1 = ld4(t + (size_t)e1.x * 32 + q * 4);
        float4 v2 = ld4(t + (size_t)e2.x * 32 + q * 4);
        float4 v3 = ld4(t + (size_t)e3.x * 32 + q * 4);
        fma4s(acc0, __int_as_float(e0.y), v0);
        fma4s(acc1, __int_as_float(e1.y), v1);
        fma4s(acc2, __int_as_float(e2.y), v2);
        fma4s(acc3, __int_as_float(e3.y), v3);
    }
    for (; i < end; ++i) {
        int2 e0 = entries[i];
        fma4s(acc0, __int_as_float(e0.y), ld4(t + (size_t)e0.x * 32 + q * 4));
    }
    acc0.x += acc1.x + acc2.x + acc3.x;
    acc0.y += acc1.y + acc2.y + acc3.y;
    acc0.z += acc1.z + acc2.z + acc3.z;
    acc0.w += acc1.w + acc2.w + acc3.w;
    float4 r = make_float4(scale * acc0.x, scale * acc0.y, scale * acc0.z, scale * acc0.w);
    if (sub) {
        float4 s4 = ld4(sub + (size_t)n * 32 + q * 4);
        r.x -= s4.x; r.y -= s4.y; r.z -= s4.z; r.w -= s4.w;
    }
    if (outf) *reinterpret_cast<float4*>(outf + (size_t)n * 32 + q * 4) = r;
    short4 rb;
    rb.x = f2bf(r.x); rb.y = f2bf(r.y); rb.z = f2bf(r.z); rb.w = f2bf(r.w);
    *reinterpret_cast<short4*>(outb + (size_t)n * 32 + q * 4) = rb;
}

// x (f32) -> bf16
__global__ void k_xb(const float* __restrict__ x, short* __restrict__ xb, int n4) {
    int i = blockIdx.x * blockDim.x + threadIdx.x;
    if (i >= n4) return;
    float4 v = ld4(x + (size_t)i * 4);
    short4 rb;
    rb.x = f2bf(v.x); rb.y = f2bf(v.y); rb.z = f2bf(v.z); rb.w = f2bf(v.w);
    *reinterpret_cast<short4*>(xb + (size_t)i * 4) = rb;
}

// prepack W into bf16 B-fragments.
// P[(nt*4+kt)*64 + lane][j] = Wx[gate(nt)][kt][(lane>>4)*8+j][(nt&3)*16+(lane&15)]
// nt 0-3: gate I (0); 4-7: gate C (2); 8-11: gate O (3). cols 0..191 = [I|C|O].
__global__ void k_prepack(const float* __restrict__ Wx, short* __restrict__ P) {
    int t = blockIdx.x * blockDim.x + threadIdx.x;
    if (t >= 12 * 4 * 64) return;
    int lane = t & 63;
    int kt = (t >> 6) & 3;
    int nt = t >> 8;
    int gate = (nt < 4) ? 0 : (nt < 8) ? 2 : 3;
    int h = (nt & 3) * 16 + (lane & 15);
    int fb = (lane >> 4) * 8;
    short8v v;
#pragma unroll
    for (int j = 0; j < 8; ++j)
        v[j] = f2bf(Wx[((size_t)(gate * 4 + kt) * 32 + fb + j) * 64 + h]);
    *(reinterpret_cast<short8v*>(P) + t) = v;
}

__device__ __forceinline__ float sigf(float x) {
    return __builtin_amdgcn_rcpf(1.f + __builtin_amdgcn_exp2f(-1.4426950408889634f * x));
}
__device__ __forceinline__ float tanhf_fast(float x) {
    float e = __builtin_amdgcn_exp2f(2.8853900817779268f * x);
    return 1.f - 2.f * __builtin_amdgcn_rcpf(e + 1.f);
}

// MFMA gates GEMM + LSTM pointwise + linear head.
// Block 256 (4 waves), 16 nodes/wave. Per wave: A = 4 k-tiles of 16 nodes
// (in regs, direct 16B loads), B = prepacked W frags, 12 nt x 4 kt mfma.
__global__ __launch_bounds__(256)
void k_final_mfma(const short* __restrict__ xb, const short* __restrict__ t1b,
                  const short* __restrict__ t2b, const short* __restrict__ t3b,
                  const short* __restrict__ P, const float* __restrict__ bx,
                  const float* __restrict__ bh, const float* __restrict__ wc,
                  const float* __restrict__ bg, const float* __restrict__ lin_w,
                  const float* __restrict__ lin_b, float* __restrict__ out, int N) {
    const int wave = threadIdx.x >> 6, lane = threadIdx.x & 63;
    const int nb = blockIdx.x * 64 + wave * 16;
    const int rc = min(nb + (lane & 15), N - 1);
    const int ko = (lane >> 4) * 8;

    short8v A0 = *reinterpret_cast<const short8v*>(xb  + (size_t)rc * 32 + ko);
    short8v A1 = *reinterpret_cast<const short8v*>(t1b + (size_t)rc * 32 + ko);
    short8v A2 = *reinterpret_cast<const short8v*>(t2b + (size_t)rc * 32 + ko);
    short8v A3 = *reinterpret_cast<const short8v*>(t3b + (size_t)rc * 32 + ko);

    const short8v* Pv = reinterpret_cast<const short8v*>(P);
    f32x4 acc[12];
#pragma unroll
    for (int nt = 0; nt < 12; ++nt) {
        const short8v* Pb = Pv + (size_t)nt * 4 * 64 + lane;
        f32x4 a = {0.f, 0.f, 0.f, 0.f};
        a = __builtin_amdgcn_mfma_f32_16x16x32_bf16(A0, Pb[0],   a, 0, 0, 0);
        a = __builtin_amdgcn_mfma_f32_16x16x32_bf16(A1, Pb[64],  a, 0, 0, 0);
        a = __builtin_amdgcn_mfma_f32_16x16x32_bf16(A2, Pb[128], a, 0, 0, 0);
        a = __builtin_amdgcn_mfma_f32_16x16x32_bf16(A3, Pb[192], a, 0, 0, 0);
        acc[nt] = a;
    }

    const int hq = lane & 15;
    const int ng = lane >> 4;
    const float lb = lin_b[0];
    float p[4] = {0.f, 0.f, 0.f, 0.f};
#pragma unroll
    for (int ht = 0; ht < 4; ++ht) {
        int h = ht * 16 + hq;
        float bI = bx[h] + bh[h] + bg[h];
        float bC = bx[128 + h] + bh[128 + h] + bg[128 + h];
        float bO = bx[192 + h] + bh[192 + h] + bg[192 + h];
        float w2 = wc[128 + h];
        float lw = lin_w[h];
#pragma unroll
        for (int r = 0; r < 4; ++r) {
            float I = sigf(acc[ht][r] + bI);
            float T = tanhf_fast(acc[4 + ht][r] + bC);
            float C = I * T;
            float O = sigf(acc[8 + ht][r] + bO + w2 * C);
            float H = O * tanhf_fast(C);
            p[r] = fmaf(H, lw, p[r]);
        }
    }
#pragma unroll
    for (int r = 0; r < 4; ++r) {
        float v = p[r];
        v += __shfl_xor(v, 1);
        v += __shfl_xor(v, 2);
        v += __shfl_xor(v, 4);
        v += __shfl_xor(v, 8);
        if (hq == 0) {
            int n = nb + ng * 4 + r;
            if (n < N) out[n] = v + lb;
        }
    }
}

extern "C" void kernel_launch(void* const* d_in, const int* in_sizes, int n_in,
                              void* d_out, int out_size, void* d_ws, size_t ws_size,
                              hipStream_t stream) {
    const float* x   = (const float*)d_in[0];
    const int*   ei  = (const int*)d_in[1];
    const float* ew  = (const float*)d_in[2];
    const float* Wx  = (const float*)d_in[3];
    const float* bx  = (const float*)d_in[4];
    // d_in[5] = Wh (unused: zero initial state)
    const float* bh  = (const float*)d_in[6];
    const float* wcp = (const float*)d_in[7];
    const float* bg  = (const float*)d_in[8];
    const float* lw  = (const float*)d_in[9];
    const float* lb  = (const float*)d_in[10];
    float* out = (float*)d_out;

    const int N  = in_sizes[0] / 32;
    const int nE = in_sizes[2];
    const int* src = ei;
    const int* dst = ei + nE;

    char* ws = (char*)d_ws;
    size_t off = 0;
    float* dinv    = (float*)(ws + off); off += (size_t)N * 4;
    int*   cnt     = (int*)(ws + off);   off += (size_t)N * 4;
    int*   rowptr  = (int*)(ws + off);   off += (size_t)N * 4;
    int*   partials= (int*)(ws + off);   off += 1024 * 4;
    short* P       = (short*)(ws + off); off += 12 * 4 * 64 * 8 * 2;
    int2*  entries = (int2*)(ws + off);  off += (size_t)nE * 8;
    float* Tx1f    = (float*)(ws + off); off += (size_t)N * 32 * 4;
    float* Tx2f    = (float*)(ws + off); off += (size_t)N * 32 * 4;
    short* xbuf    = (short*)(ws + off); off += (size_t)N * 32 * 2;
    short* Tx1b    = (short*)(ws + off); off += (size_t)N * 32 * 2;
    short* Tx2b    = (short*)(ws + off); off += (size_t)N * 32 * 2;
    short* Tx3b    = (short*)(ws + off); off += (size_t)N * 32 * 2;

    // partials alias Tx1f/Tx2f (dead until gathers): NCH*N floats/ints each
    float* degPart = Tx1f;
    int*   cntPart = (int*)Tx2f;

    const int nb = (N + NT - 1) / NT;
    const int nRange = (N + RS - 1) / RS;

    k_hist<<<nRange * NCH, 1024, 0, stream>>>(src, dst, ew, degPart, cntPart, nE, N);
    k_prepack<<<(12 * 4 * 64 + NT - 1) / NT, NT, 0, stream>>>(Wx, P);
    k_xb<<<(N * 8 + NT - 1) / NT, NT, 0, stream>>>(x, xbuf, N * 8);
    k_reduce<<<nb, NT, 0, stream>>>(degPart, cntPart, dinv, cnt, N);
    k_scanA<<<nb, NT, 0, stream>>>(cnt, rowptr, partials, N);
    k_scanB<<<1, 1024, 0, stream>>>(partials, nb);
    k_scanC<<<nb, NT, 0, stream>>>(rowptr, partials, N);
    k_scan_off<<<nb, NT, 0, stream>>>(cntPart, rowptr, N);
    k_fill2<<<nRange * NCH, 1024, 0, stream>>>(src, dst, ew, dinv, cntPart,
                                               entries, nE, N);

    const int gb = (N * 8 + NT - 1) / NT;
    k_gather<<<gb, NT, 0, stream>>>(x,    nullptr, Tx1f,    Tx1b, rowptr, cnt, entries, 1.f, N);
    k_gather<<<gb, NT, 0, stream>>>(Tx1f, x,       Tx2f,    Tx2b, rowptr, cnt, entries, 2.f, N);
    k_gather<<<gb, NT, 0, stream>>>(Tx2f, Tx1f,    nullptr, Tx3b, rowptr, cnt, entries, 2.f, N);

    const int fb = (N + 63) / 64;
    k_final_mfma<<<fb, NT, 0, stream>>>(xbuf, Tx1b, Tx2b, Tx3b, P, bx, bh, wcp,
                                        bg, lw, lb, out, N);
}

// Round 9
// 119.040 us; speedup vs baseline: 1.9037x; 1.2197x over previous
//
#include <hip/hip_runtime.h>
#include <math.h>

// GConvLSTM single step from zero state + linear head.
// H=C=0 initially => cheb_conv(H)=bh[g], F-gate irrelevant.
//   I = sigmoid(chebX_0 + bx0+bh0+bg0)
//   T = tanh   (chebX_2 + bx2+bh2+bg2)
//   C = I*T
//   O = sigmoid(chebX_3 + bx3+bh3+bg3 + wc2*C)
//   out = (O*tanh(C)) @ lin_w + lin_b
//
// R2: push->pull CSR gather.  R3: hw transcendentals.
// R7: zero global atomics (LDS histograms + counting-sort fill).
// R8: k_final via bf16 MFMA (verified fragment layouts).
// R9: bf16 Chebyshev recursion (f32 accumulate): feature table 3.2MB < 4MB
//     per-XCD L2 -> random gathers become L2 hits; no f32 Tx stores at all.
//     Fused k_reduce+scanA and k_scanC+scan_off (fewer launches/passes).

#define NT 256
#define RS 8192     // nodes per range (LDS histogram size)
#define NCH 32      // edge chunks

typedef __attribute__((ext_vector_type(8))) short short8v;
typedef __attribute__((ext_vector_type(8))) unsigned short ushort8v;
typedef __attribute__((ext_vector_type(4))) float f32x4;

__device__ __forceinline__ short f2bf(float f) {
    unsigned u = __float_as_uint(f);
    u += 0x7FFFu + ((u >> 16) & 1u);   // round-to-nearest-even
    return (short)(u >> 16);
}
__device__ __forceinline__ float bf2f(unsigned short b) {
    return __uint_as_float((unsigned)b << 16);
}

// per-(range, chunk) LDS histogram of deg(by src) and cnt(by dst);
// non-atomic flush to per-chunk partials.
__global__ __launch_bounds__(1024)
void k_hist(const int* __restrict__ src, const int* __restrict__ dst,
            const float* __restrict__ w, float* __restrict__ degPart,
            int* __restrict__ cntPart, int nE, int N) {
    __shared__ float s_deg[RS];
    __shared__ int   s_cnt[RS];
    const int r = blockIdx.x / NCH, b = blockIdx.x % NCH;
    const int base = r * RS;
    for (int i = threadIdx.x; i < RS; i += 1024) { s_deg[i] = 0.f; s_cnt[i] = 0; }
    __syncthreads();
    const int chunk = (nE + NCH - 1) / NCH;
    const int e0 = b * chunk, e1 = min(e0 + chunk, nE);
    for (int e = e0 + (int)threadIdx.x; e < e1; e += 1024) {
        int s = src[e], d = dst[e];
        unsigned so = (unsigned)(s - base), dof = (unsigned)(d - base);
        if (so < RS) atomicAdd(&s_deg[so], w[e]);
        if (dof < RS) atomicAdd(&s_cnt[dof], 1);
    }
    __syncthreads();
    for (int i = threadIdx.x; i < RS; i += 1024) {
        int n = base + i;
        if (n < N) {
            degPart[(size_t)b * N + n] = s_deg[i];
            cntPart[(size_t)b * N + n] = s_cnt[i];
        }
    }
}

// fused: reduce partials -> dinv/cnt, then block-local exclusive scan of cnt
__global__ __launch_bounds__(NT)
void k_reduce_scanA(const float* __restrict__ degPart, const int* __restrict__ cntPart,
                    float* __restrict__ dinv, int* __restrict__ cnt,
                    int* __restrict__ rowptr, int* __restrict__ partials, int N) {
    __shared__ int s[NT];
    int t = threadIdx.x, i = blockIdx.x * NT + t;
    int c = 0;
    if (i < N) {
        float d = 0.f;
#pragma unroll
        for (int b = 0; b < NCH; ++b) {
            d += degPart[(size_t)b * N + i];
            c += cntPart[(size_t)b * N + i];
        }
        dinv[i] = d > 0.f ? rsqrtf(d) : 0.f;
        cnt[i] = c;
    }
    s[t] = c;
    __syncthreads();
    for (int off = 1; off < NT; off <<= 1) {
        int u = (t >= off) ? s[t - off] : 0;
        __syncthreads();
        s[t] += u;
        __syncthreads();
    }
    if (i < N) rowptr[i] = s[t] - c;
    if (t == NT - 1) partials[blockIdx.x] = s[t];
}

__global__ void k_scanB(int* __restrict__ partials, int nb) {
    __shared__ int s[1024];
    int t = threadIdx.x;
    int v = (t < nb) ? partials[t] : 0;
    s[t] = v;
    __syncthreads();
    for (int off = 1; off < 1024; off <<= 1) {
        int u = (t >= off) ? s[t - off] : 0;
        __syncthreads();
        s[t] += u;
        __syncthreads();
    }
    if (t < nb) partials[t] = s[t] - v;
}

// fused: add block offset to rowptr, then chunk-axis exclusive scan into
// per-chunk slot offsets (cntPart becomes offsets).
__global__ void k_scanC_off(int* __restrict__ rowptr, const int* __restrict__ partials,
                            int* __restrict__ cntPart, int N) {
    int n = blockIdx.x * NT + threadIdx.x;
    if (n >= N) return;
    int v = rowptr[n] + partials[blockIdx.x];
    rowptr[n] = v;
    int s = v;
#pragma unroll
    for (int b = 0; b < NCH; ++b) {
        int t = cntPart[(size_t)b * N + n];
        cntPart[(size_t)b * N + n] = s;
        s += t;
    }
}

__global__ __launch_bounds__(1024)
void k_fill2(const int* __restrict__ src, const int* __restrict__ dst,
             const float* __restrict__ w, const float* __restrict__ dinv,
             const int* __restrict__ offs, int2* __restrict__ entries,
             int nE, int N) {
    __shared__ int s_cur[RS];
    const int r = blockIdx.x / NCH, b = blockIdx.x % NCH;
    const int base = r * RS;
    for (int i = threadIdx.x; i < RS; i += 1024) {
        int n = base + i;
        s_cur[i] = (n < N) ? offs[(size_t)b * N + n] : 0;
    }
    __syncthreads();
    const int chunk = (nE + NCH - 1) / NCH;
    const int e0 = b * chunk, e1 = min(e0 + chunk, nE);
    for (int e = e0 + (int)threadIdx.x; e < e1; e += 1024) {
        int d = dst[e];
        unsigned dof = (unsigned)(d - base);
        if (dof < RS) {
            int s = src[e];
            float nv = -dinv[s] * w[e] * dinv[d];
            int pos = atomicAdd(&s_cur[dof], 1);
            entries[pos] = make_int2(s, __float_as_int(nv));
        }
    }
}

__device__ __forceinline__ void bf8_fma(float* acc, ushort8v v, float s) {
#pragma unroll
    for (int j = 0; j < 8; ++j)
        acc[j] = fmaf(s, bf2f(v[j]), acc[j]);
}

// bf16-table gather, f32 accumulate, bf16 output. 4 threads/node (8 feats ea).
// out[n][q*8..] = scale * sum_e norm_e * tb[src_e] - sub[n]
__global__ __launch_bounds__(256)
void k_gather_bf(const unsigned short* __restrict__ tb,
                 const float* __restrict__ subf,
                 const unsigned short* __restrict__ subb,
                 short* __restrict__ outb,
                 const int* __restrict__ rowptr, const int* __restrict__ cnt,
                 const int2* __restrict__ entries, float scale, int N) {
    int idx = blockIdx.x * blockDim.x + threadIdx.x;
    if (idx >= N * 4) return;
    int n = idx >> 2, q = idx & 3;
    int beg = rowptr[n], end = beg + cnt[n];
    float acc0[8] = {0, 0, 0, 0, 0, 0, 0, 0};
    float acc1[8] = {0, 0, 0, 0, 0, 0, 0, 0};
    int i = beg;
    for (; i + 3 < end; i += 4) {
        int2 e0 = entries[i];
        int2 e1 = entries[i + 1];
        int2 e2 = entries[i + 2];
        int2 e3 = entries[i + 3];
        ushort8v v0 = *reinterpret_cast<const ushort8v*>(tb + (size_t)e0.x * 32 + q * 8);
        ushort8v v1 = *reinterpret_cast<const ushort8v*>(tb + (size_t)e1.x * 32 + q * 8);
        ushort8v v2 = *reinterpret_cast<const ushort8v*>(tb + (size_t)e2.x * 32 + q * 8);
        ushort8v v3 = *reinterpret_cast<const ushort8v*>(tb + (size_t)e3.x * 32 + q * 8);
        bf8_fma(acc0, v0, __int_as_float(e0.y));
        bf8_fma(acc1, v1, __int_as_float(e1.y));
        bf8_fma(acc0, v2, __int_as_float(e2.y));
        bf8_fma(acc1, v3, __int_as_float(e3.y));
    }
    for (; i < end; ++i) {
        int2 e0 = entries[i];
        ushort8v v0 = *reinterpret_cast<const ushort8v*>(tb + (size_t)e0.x * 32 + q * 8);
        bf8_fma(acc0, v0, __int_as_float(e0.y));
    }
    float r[8];
#pragma unroll
    for (int j = 0; j < 8; ++j) r[j] = scale * (acc0[j] + acc1[j]);
    if (subf) {
#pragma unroll
        for (int j = 0; j < 8; ++j) r[j] -= subf[(size_t)n * 32 + q * 8 + j];
    } else if (subb) {
        ushort8v sv = *reinterpret_cast<const ushort8v*>(subb + (size_t)n * 32 + q * 8);
#pragma unroll
        for (int j = 0; j < 8; ++j) r[j] -= bf2f(sv[j]);
    }
    short8v rb;
#pragma unroll
    for (int j = 0; j < 8; ++j) rb[j] = f2bf(r[j]);
    *reinterpret_cast<short8v*>(outb + (size_t)n * 32 + q * 8) = rb;
}

// x (f32) -> bf16
__global__ void k_xb(const float* __restrict__ x, short* __restrict__ xb, int n4) {
    int i = blockIdx.x * blockDim.x + threadIdx.x;
    if (i >= n4) return;
    const float4 v = *reinterpret_cast<const float4*>(x + (size_t)i * 4);
    short4 rb;
    rb.x = f2bf(v.x); rb.y = f2bf(v.y); rb.z = f2bf(v.z); rb.w = f2bf(v.w);
    *reinterpret_cast<short4*>(xb + (size_t)i * 4) = rb;
}

// prepack W into bf16 B-fragments.
// P[(nt*4+kt)*64 + lane][j] = Wx[gate(nt)][kt][(lane>>4)*8+j][(nt&3)*16+(lane&15)]
// nt 0-3: gate I (0); 4-7: gate C (2); 8-11: gate O (3).
__global__ void k_prepack(const float* __restrict__ Wx, short* __restrict__ P) {
    int t = blockIdx.x * blockDim.x + threadIdx.x;
    if (t >= 12 * 4 * 64) return;
    int lane = t & 63;
    int kt = (t >> 6) & 3;
    int nt = t >> 8;
    int gate = (nt < 4) ? 0 : (nt < 8) ? 2 : 3;
    int h = (nt & 3) * 16 + (lane & 15);
    int fb = (lane >> 4) * 8;
    short8v v;
#pragma unroll
    for (int j = 0; j < 8; ++j)
        v[j] = f2bf(Wx[((size_t)(gate * 4 + kt) * 32 + fb + j) * 64 + h]);
    *(reinterpret_cast<short8v*>(P) + t) = v;
}

__device__ __forceinline__ float sigf(float x) {
    return __builtin_amdgcn_rcpf(1.f + __builtin_amdgcn_exp2f(-1.4426950408889634f * x));
}
__device__ __forceinline__ float tanhf_fast(float x) {
    float e = __builtin_amdgcn_exp2f(2.8853900817779268f * x);
    return 1.f - 2.f * __builtin_amdgcn_rcpf(e + 1.f);
}

// MFMA gates GEMM + LSTM pointwise + linear head.
// Block 256 (4 waves), 16 nodes/wave. A row=lane&15, k=(lane>>4)*8+j;
// D col=lane&15, row=(lane>>4)*4+reg.
__global__ __launch_bounds__(256)
void k_final_mfma(const short* __restrict__ xb, const short* __restrict__ t1b,
                  const short* __restrict__ t2b, const short* __restrict__ t3b,
                  const short* __restrict__ P, const float* __restrict__ bx,
                  const float* __restrict__ bh, const float* __restrict__ wc,
                  const float* __restrict__ bg, const float* __restrict__ lin_w,
                  const float* __restrict__ lin_b, float* __restrict__ out, int N) {
    const int wave = threadIdx.x >> 6, lane = threadIdx.x & 63;
    const int nb = blockIdx.x * 64 + wave * 16;
    const int rc = min(nb + (lane & 15), N - 1);
    const int ko = (lane >> 4) * 8;

    short8v A0 = *reinterpret_cast<const short8v*>(xb  + (size_t)rc * 32 + ko);
    short8v A1 = *reinterpret_cast<const short8v*>(t1b + (size_t)rc * 32 + ko);
    short8v A2 = *reinterpret_cast<const short8v*>(t2b + (size_t)rc * 32 + ko);
    short8v A3 = *reinterpret_cast<const short8v*>(t3b + (size_t)rc * 32 + ko);

    const short8v* Pv = reinterpret_cast<const short8v*>(P);
    f32x4 acc[12];
#pragma unroll
    for (int nt = 0; nt < 12; ++nt) {
        const short8v* Pb = Pv + (size_t)nt * 4 * 64 + lane;
        f32x4 a = {0.f, 0.f, 0.f, 0.f};
        a = __builtin_amdgcn_mfma_f32_16x16x32_bf16(A0, Pb[0],   a, 0, 0, 0);
        a = __builtin_amdgcn_mfma_f32_16x16x32_bf16(A1, Pb[64],  a, 0, 0, 0);
        a = __builtin_amdgcn_mfma_f32_16x16x32_bf16(A2, Pb[128], a, 0, 0, 0);
        a = __builtin_amdgcn_mfma_f32_16x16x32_bf16(A3, Pb[192], a, 0, 0, 0);
        acc[nt] = a;
    }

    const int hq = lane & 15;
    const int ng = lane >> 4;
    const float lb = lin_b[0];
    float p[4] = {0.f, 0.f, 0.f, 0.f};
#pragma unroll
    for (int ht = 0; ht < 4; ++ht) {
        int h = ht * 16 + hq;
        float bI = bx[h] + bh[h] + bg[h];
        float bC = bx[128 + h] + bh[128 + h] + bg[128 + h];
        float bO = bx[192 + h] + bh[192 + h] + bg[192 + h];
        float w2 = wc[128 + h];
        float lw = lin_w[h];
#pragma unroll
        for (int r = 0; r < 4; ++r) {
            float I = sigf(acc[ht][r] + bI);
            float T = tanhf_fast(acc[4 + ht][r] + bC);
            float C = I * T;
            float O = sigf(acc[8 + ht][r] + bO + w2 * C);
            float H = O * tanhf_fast(C);
            p[r] = fmaf(H, lw, p[r]);
        }
    }
#pragma unroll
    for (int r = 0; r < 4; ++r) {
        float v = p[r];
        v += __shfl_xor(v, 1);
        v += __shfl_xor(v, 2);
        v += __shfl_xor(v, 4);
        v += __shfl_xor(v, 8);
        if (hq == 0) {
            int n = nb + ng * 4 + r;
            if (n < N) out[n] = v + lb;
        }
    }
}

extern "C" void kernel_launch(void* const* d_in, const int* in_sizes, int n_in,
                              void* d_out, int out_size, void* d_ws, size_t ws_size,
                              hipStream_t stream) {
    const float* x   = (const float*)d_in[0];
    const int*   ei  = (const int*)d_in[1];
    const float* ew  = (const float*)d_in[2];
    const float* Wx  = (const float*)d_in[3];
    const float* bx  = (const float*)d_in[4];
    // d_in[5] = Wh (unused: zero initial state)
    const float* bh  = (const float*)d_in[6];
    const float* wcp = (const float*)d_in[7];
    const float* bg  = (const float*)d_in[8];
    const float* lw  = (const float*)d_in[9];
    const float* lb  = (const float*)d_in[10];
    float* out = (float*)d_out;

    const int N  = in_sizes[0] / 32;
    const int nE = in_sizes[2];
    const int* src = ei;
    const int* dst = ei + nE;

    char* ws = (char*)d_ws;
    size_t off = 0;
    float* dinv    = (float*)(ws + off); off += (size_t)N * 4;
    int*   cnt     = (int*)(ws + off);   off += (size_t)N * 4;
    int*   rowptr  = (int*)(ws + off);   off += (size_t)N * 4;
    int*   partials= (int*)(ws + off);   off += 1024 * 4;
    short* P       = (short*)(ws + off); off += 12 * 4 * 64 * 8 * 2;
    int2*  entries = (int2*)(ws + off);  off += (size_t)nE * 8;
    float* degPart = (float*)(ws + off); off += (size_t)NCH * N * 4;
    int*   cntPart = (int*)(ws + off);   off += (size_t)NCH * N * 4;
    short* xbuf    = (short*)(ws + off); off += (size_t)N * 32 * 2;
    short* Tx1b    = (short*)(ws + off); off += (size_t)N * 32 * 2;
    short* Tx2b    = (short*)(ws + off); off += (size_t)N * 32 * 2;
    short* Tx3b    = (short*)(ws + off); off += (size_t)N * 32 * 2;

    const int nb = (N + NT - 1) / NT;
    const int nRange = (N + RS - 1) / RS;

    k_hist<<<nRange * NCH, 1024, 0, stream>>>(src, dst, ew, degPart, cntPart, nE, N);
    k_prepack<<<(12 * 4 * 64 + NT - 1) / NT, NT, 0, stream>>>(Wx, P);
    k_xb<<<(N * 8 + NT - 1) / NT, NT, 0, stream>>>(x, xbuf, N * 8);
    k_reduce_scanA<<<nb, NT, 0, stream>>>(degPart, cntPart, dinv, cnt, rowptr,
                                          partials, N);
    k_scanB<<<1, 1024, 0, stream>>>(partials, nb);
    k_scanC_off<<<nb, NT, 0, stream>>>(rowptr, partials, cntPart, N);
    k_fill2<<<nRange * NCH, 1024, 0, stream>>>(src, dst, ew, dinv, cntPart,
                                               entries, nE, N);

    const int gb = (N * 4 + NT - 1) / NT;
    k_gather_bf<<<gb, NT, 0, stream>>>((const unsigned short*)xbuf, nullptr, nullptr,
                                       Tx1b, rowptr, cnt, entries, 1.f, N);
    k_gather_bf<<<gb, NT, 0, stream>>>((const unsigned short*)Tx1b, x, nullptr,
                                       Tx2b, rowptr, cnt, entries, 2.f, N);
    k_gather_bf<<<gb, NT, 0, stream>>>((const unsigned short*)Tx2b, nullptr,
                                       (const unsigned short*)Tx1b,
                                       Tx3b, rowptr, cnt, entries, 2.f, N);

    const int fb = (N + 63) / 64;
    k_final_mfma<<<fb, NT, 0, stream>>>(xbuf, Tx1b, Tx2b, Tx3b, P, bx, bh, wcp,
                                        bg, lw, lb, out, N);
}

// Round 10
// 118.313 us; speedup vs baseline: 1.9153x; 1.0061x over previous
//
#include <hip/hip_runtime.h>
#include <math.h>

// GConvLSTM single step from zero state + linear head.
// H=C=0 initially => cheb_conv(H)=bh[g], F-gate irrelevant.
//   I = sigmoid(chebX_0 + bx0+bh0+bg0)
//   T = tanh   (chebX_2 + bx2+bh2+bg2)
//   C = I*T
//   O = sigmoid(chebX_3 + bx3+bh3+bg3 + wc2*C)
//   out = (O*tanh(C)) @ lin_w + lin_b
//
// R2: push->pull CSR gather.  R3: hw transcendentals.
// R7: zero global atomics (LDS histograms + counting-sort fill).
// R8: k_final via bf16 MFMA.  R9: bf16 Chebyshev recursion (3.2MB table).
// R10: RSH=16384 (128KB LDS hist, 4 edge passes not 7); gather entry-parity
//      split (8 thr/node, chain halved, shfl_xor(4) combine); gather3 fused
//      into k_final (prop(Tx2) lands directly in the A3 MFMA fragment);
//      prepack+xb fused; gather2 subtrahend = bf16 xbuf.

#define NT 256
#define RSH 16384   // hist range: 128KB LDS/block
#define RSF 16384   // fill range: 64KB LDS/block
#define NCH 32      // edge chunks

typedef __attribute__((ext_vector_type(8))) short short8v;
typedef __attribute__((ext_vector_type(8))) unsigned short ushort8v;
typedef __attribute__((ext_vector_type(4))) float f32x4;

__device__ __forceinline__ short f2bf(float f) {
    unsigned u = __float_as_uint(f);
    u += 0x7FFFu + ((u >> 16) & 1u);   // round-to-nearest-even
    return (short)(u >> 16);
}
__device__ __forceinline__ float bf2f(unsigned short b) {
    return __uint_as_float((unsigned)b << 16);
}

// per-(range, chunk) LDS histogram of deg(by src) and cnt(by dst)
__global__ __launch_bounds__(1024)
void k_hist(const int* __restrict__ src, const int* __restrict__ dst,
            const float* __restrict__ w, float* __restrict__ degPart,
            int* __restrict__ cntPart, int nE, int N) {
    __shared__ float s_deg[RSH];
    __shared__ int   s_cnt[RSH];
    const int r = blockIdx.x / NCH, b = blockIdx.x % NCH;
    const int base = r * RSH;
    for (int i = threadIdx.x; i < RSH; i += 1024) { s_deg[i] = 0.f; s_cnt[i] = 0; }
    __syncthreads();
    const int chunk = (nE + NCH - 1) / NCH;
    const int e0 = b * chunk, e1 = min(e0 + chunk, nE);
    for (int e = e0 + (int)threadIdx.x; e < e1; e += 1024) {
        int s = src[e], d = dst[e];
        unsigned so = (unsigned)(s - base), dof = (unsigned)(d - base);
        if (so < RSH) atomicAdd(&s_deg[so], w[e]);
        if (dof < RSH) atomicAdd(&s_cnt[dof], 1);
    }
    __syncthreads();
    const int lim = min(RSH, N - base);
    for (int i = threadIdx.x; i < lim; i += 1024) {
        degPart[(size_t)b * N + base + i] = s_deg[i];
        cntPart[(size_t)b * N + base + i] = s_cnt[i];
    }
}

// fused: reduce partials -> dinv/cnt, block-local exclusive scan of cnt
__global__ __launch_bounds__(NT)
void k_reduce_scanA(const float* __restrict__ degPart, const int* __restrict__ cntPart,
                    float* __restrict__ dinv, int* __restrict__ cnt,
                    int* __restrict__ rowptr, int* __restrict__ partials, int N) {
    __shared__ int s[NT];
    int t = threadIdx.x, i = blockIdx.x * NT + t;
    int c = 0;
    if (i < N) {
        float d = 0.f;
#pragma unroll
        for (int b = 0; b < NCH; ++b) {
            d += degPart[(size_t)b * N + i];
            c += cntPart[(size_t)b * N + i];
        }
        dinv[i] = d > 0.f ? rsqrtf(d) : 0.f;
        cnt[i] = c;
    }
    s[t] = c;
    __syncthreads();
    for (int off = 1; off < NT; off <<= 1) {
        int u = (t >= off) ? s[t - off] : 0;
        __syncthreads();
        s[t] += u;
        __syncthreads();
    }
    if (i < N) rowptr[i] = s[t] - c;
    if (t == NT - 1) partials[blockIdx.x] = s[t];
}

__global__ void k_scanB(int* __restrict__ partials, int nb) {
    __shared__ int s[1024];
    int t = threadIdx.x;
    int v = (t < nb) ? partials[t] : 0;
    s[t] = v;
    __syncthreads();
    for (int off = 1; off < 1024; off <<= 1) {
        int u = (t >= off) ? s[t - off] : 0;
        __syncthreads();
        s[t] += u;
        __syncthreads();
    }
    if (t < nb) partials[t] = s[t] - v;
}

// fused: finalize rowptr, then chunk-axis exclusive scan -> per-chunk offsets
__global__ void k_scanC_off(int* __restrict__ rowptr, const int* __restrict__ partials,
                            int* __restrict__ cntPart, int N) {
    int n = blockIdx.x * NT + threadIdx.x;
    if (n >= N) return;
    int v = rowptr[n] + partials[blockIdx.x];
    rowptr[n] = v;
    int s = v;
#pragma unroll
    for (int b = 0; b < NCH; ++b) {
        int t = cntPart[(size_t)b * N + n];
        cntPart[(size_t)b * N + n] = s;
        s += t;
    }
}

__global__ __launch_bounds__(1024)
void k_fill2(const int* __restrict__ src, const int* __restrict__ dst,
             const float* __restrict__ w, const float* __restrict__ dinv,
             const int* __restrict__ offs, int2* __restrict__ entries,
             int nE, int N) {
    __shared__ int s_cur[RSF];
    const int r = blockIdx.x / NCH, b = blockIdx.x % NCH;
    const int base = r * RSF;
    const int lim = min(RSF, N - base);
    for (int i = threadIdx.x; i < lim; i += 1024)
        s_cur[i] = offs[(size_t)b * N + base + i];
    __syncthreads();
    const int chunk = (nE + NCH - 1) / NCH;
    const int e0 = b * chunk, e1 = min(e0 + chunk, nE);
    for (int e = e0 + (int)threadIdx.x; e < e1; e += 1024) {
        int d = dst[e];
        unsigned dof = (unsigned)(d - base);
        if (dof < RSF) {
            int s = src[e];
            float nv = -dinv[s] * w[e] * dinv[d];
            int pos = atomicAdd(&s_cur[dof], 1);
            entries[pos] = make_int2(s, __float_as_int(nv));
        }
    }
}

__device__ __forceinline__ void bf8_fma(float* acc, ushort8v v, float s) {
#pragma unroll
    for (int j = 0; j < 8; ++j)
        acc[j] = fmaf(s, bf2f(v[j]), acc[j]);
}

// bf16-table gather, f32 accumulate, bf16 out. 8 threads/node:
// tq = idx&3 (8-feature slice), half = (idx>>2)&1 (entry parity).
// Chain halved vs 4-thread layout; halves combined via shfl_xor(4).
__global__ __launch_bounds__(256)
void k_gather_bf(const unsigned short* __restrict__ tb,
                 const unsigned short* __restrict__ subb,
                 short* __restrict__ outb,
                 const int* __restrict__ rowptr, const int* __restrict__ cnt,
                 const int2* __restrict__ entries, float scale, int N) {
    int idx = blockIdx.x * blockDim.x + threadIdx.x;
    if (idx >= N * 8) return;
    int n = idx >> 3, tq = idx & 3, half = (idx >> 2) & 1;
    int beg = rowptr[n], end = beg + cnt[n];
    float acc0[8] = {0, 0, 0, 0, 0, 0, 0, 0};
    float acc1[8] = {0, 0, 0, 0, 0, 0, 0, 0};
    int i = beg + half;
    for (; i + 6 < end; i += 8) {
        int2 e0 = entries[i];
        int2 e1 = entries[i + 2];
        int2 e2 = entries[i + 4];
        int2 e3 = entries[i + 6];
        ushort8v v0 = *reinterpret_cast<const ushort8v*>(tb + (size_t)e0.x * 32 + tq * 8);
        ushort8v v1 = *reinterpret_cast<const ushort8v*>(tb + (size_t)e1.x * 32 + tq * 8);
        ushort8v v2 = *reinterpret_cast<const ushort8v*>(tb + (size_t)e2.x * 32 + tq * 8);
        ushort8v v3 = *reinterpret_cast<const ushort8v*>(tb + (size_t)e3.x * 32 + tq * 8);
        bf8_fma(acc0, v0, __int_as_float(e0.y));
        bf8_fma(acc1, v1, __int_as_float(e1.y));
        bf8_fma(acc0, v2, __int_as_float(e2.y));
        bf8_fma(acc1, v3, __int_as_float(e3.y));
    }
    for (; i < end; i += 2) {
        int2 e0 = entries[i];
        ushort8v v0 = *reinterpret_cast<const ushort8v*>(tb + (size_t)e0.x * 32 + tq * 8);
        bf8_fma(acc0, v0, __int_as_float(e0.y));
    }
    float r[8];
#pragma unroll
    for (int j = 0; j < 8; ++j) {
        r[j] = acc0[j] + acc1[j];
        r[j] += __shfl_xor(r[j], 4);   // combine entry-parity halves
    }
    if (!half) {
        if (subb) {
            ushort8v sv = *reinterpret_cast<const ushort8v*>(subb + (size_t)n * 32 + tq * 8);
#pragma unroll
            for (int j = 0; j < 8; ++j) r[j] = fmaf(scale, r[j], -bf2f(sv[j]));
        } else {
#pragma unroll
            for (int j = 0; j < 8; ++j) r[j] *= scale;
        }
        short8v rb;
#pragma unroll
        for (int j = 0; j < 8; ++j) rb[j] = f2bf(r[j]);
        *reinterpret_cast<short8v*>(outb + (size_t)n * 32 + tq * 8) = rb;
    }
}

// fused: prepack W bf16 B-fragments (first 3072 threads) + x -> bf16.
// P[(nt*4+kt)*64+lane][j] = Wx[gate(nt)][kt][(lane>>4)*8+j][(nt&3)*16+(lane&15)]
__global__ void k_prepack_xb(const float* __restrict__ Wx, short* __restrict__ P,
                             const float* __restrict__ x, short* __restrict__ xb,
                             int n4) {
    int idx = blockIdx.x * blockDim.x + threadIdx.x;
    if (idx < 12 * 4 * 64) {
        int lane = idx & 63;
        int kt = (idx >> 6) & 3;
        int nt = idx >> 8;
        int gate = (nt < 4) ? 0 : (nt < 8) ? 2 : 3;
        int h = (nt & 3) * 16 + (lane & 15);
        int fb = (lane >> 4) * 8;
        short8v v;
#pragma unroll
        for (int j = 0; j < 8; ++j)
            v[j] = f2bf(Wx[((size_t)(gate * 4 + kt) * 32 + fb + j) * 64 + h]);
        *(reinterpret_cast<short8v*>(P) + idx) = v;
        return;
    }
    int i = idx - 12 * 4 * 64;
    if (i >= n4) return;
    const float4 v = *reinterpret_cast<const float4*>(x + (size_t)i * 4);
    short4 rb;
    rb.x = f2bf(v.x); rb.y = f2bf(v.y); rb.z = f2bf(v.z); rb.w = f2bf(v.w);
    *reinterpret_cast<short4*>(xb + (size_t)i * 4) = rb;
}

__device__ __forceinline__ float sigf(float x) {
    return __builtin_amdgcn_rcpf(1.f + __builtin_amdgcn_exp2f(-1.4426950408889634f * x));
}
__device__ __forceinline__ float tanhf_fast(float x) {
    float e = __builtin_amdgcn_exp2f(2.8853900817779268f * x);
    return 1.f - 2.f * __builtin_amdgcn_rcpf(e + 1.f);
}

// fused gather3 + MFMA gates GEMM + LSTM pointwise + linear head.
// Thread = (node = lane&15, slice = lane>>4) == A-fragment layout, so
// prop(Tx2) is computed straight into the A3 fragment. A1 doubles as Tx1 sub.
__global__ __launch_bounds__(256)
void k_final_g3(const short* __restrict__ xb, const short* __restrict__ t1b,
                const unsigned short* __restrict__ t2b,
                const short* __restrict__ P,
                const int* __restrict__ rowptr, const int* __restrict__ cnt,
                const int2* __restrict__ entries,
                const float* __restrict__ bx, const float* __restrict__ bh,
                const float* __restrict__ wc, const float* __restrict__ bg,
                const float* __restrict__ lin_w, const float* __restrict__ lin_b,
                float* __restrict__ out, int N) {
    const int wave = threadIdx.x >> 6, lane = threadIdx.x & 63;
    const int nb = blockIdx.x * 64 + wave * 16;
    const int rc = min(nb + (lane & 15), N - 1);
    const int ko = (lane >> 4) * 8;

    // gather: r = prop(Tx2)[rc][ko..ko+8)
    int beg = rowptr[rc], end = beg + cnt[rc];
    float acc0[8] = {0, 0, 0, 0, 0, 0, 0, 0};
    float acc1[8] = {0, 0, 0, 0, 0, 0, 0, 0};
    int i = beg;
    for (; i + 3 < end; i += 4) {
        int2 e0 = entries[i];
        int2 e1 = entries[i + 1];
        int2 e2 = entries[i + 2];
        int2 e3 = entries[i + 3];
        ushort8v v0 = *reinterpret_cast<const ushort8v*>(t2b + (size_t)e0.x * 32 + ko);
        ushort8v v1 = *reinterpret_cast<const ushort8v*>(t2b + (size_t)e1.x * 32 + ko);
        ushort8v v2 = *reinterpret_cast<const ushort8v*>(t2b + (size_t)e2.x * 32 + ko);
        ushort8v v3 = *reinterpret_cast<const ushort8v*>(t2b + (size_t)e3.x * 32 + ko);
        bf8_fma(acc0, v0, __int_as_float(e0.y));
        bf8_fma(acc1, v1, __int_as_float(e1.y));
        bf8_fma(acc0, v2, __int_as_float(e2.y));
        bf8_fma(acc1, v3, __int_as_float(e3.y));
    }
    for (; i < end; ++i) {
        int2 e0 = entries[i];
        ushort8v v0 = *reinterpret_cast<const ushort8v*>(t2b + (size_t)e0.x * 32 + ko);
        bf8_fma(acc0, v0, __int_as_float(e0.y));
    }

    short8v A0 = *reinterpret_cast<const short8v*>(xb  + (size_t)rc * 32 + ko);
    short8v A1 = *reinterpret_cast<const short8v*>(t1b + (size_t)rc * 32 + ko);
    short8v A2 = *reinterpret_cast<const short8v*>(
        reinterpret_cast<const short*>(t2b) + (size_t)rc * 32 + ko);
    short8v A3;
#pragma unroll
    for (int j = 0; j < 8; ++j)   // Tx3 = 2*prop(Tx2) - Tx1
        A3[j] = f2bf(2.f * (acc0[j] + acc1[j]) - bf2f((unsigned short)A1[j]));

    const short8v* Pv = reinterpret_cast<const short8v*>(P);
    f32x4 acc[12];
#pragma unroll
    for (int nt = 0; nt < 12; ++nt) {
        const short8v* Pb = Pv + (size_t)nt * 4 * 64 + lane;
        f32x4 a = {0.f, 0.f, 0.f, 0.f};
        a = __builtin_amdgcn_mfma_f32_16x16x32_bf16(A0, Pb[0],   a, 0, 0, 0);
        a = __builtin_amdgcn_mfma_f32_16x16x32_bf16(A1, Pb[64],  a, 0, 0, 0);
        a = __builtin_amdgcn_mfma_f32_16x16x32_bf16(A2, Pb[128], a, 0, 0, 0);
        a = __builtin_amdgcn_mfma_f32_16x16x32_bf16(A3, Pb[192], a, 0, 0, 0);
        acc[nt] = a;
    }

    const int hq = lane & 15;
    const int ng = lane >> 4;
    const float lb = lin_b[0];
    float p[4] = {0.f, 0.f, 0.f, 0.f};
#pragma unroll
    for (int ht = 0; ht < 4; ++ht) {
        int h = ht * 16 + hq;
        float bI = bx[h] + bh[h] + bg[h];
        float bC = bx[128 + h] + bh[128 + h] + bg[128 + h];
        float bO = bx[192 + h] + bh[192 + h] + bg[192 + h];
        float w2 = wc[128 + h];
        float lw = lin_w[h];
#pragma unroll
        for (int r = 0; r < 4; ++r) {
            float I = sigf(acc[ht][r] + bI);
            float T = tanhf_fast(acc[4 + ht][r] + bC);
            float C = I * T;
            float O = sigf(acc[8 + ht][r] + bO + w2 * C);
            float H = O * tanhf_fast(C);
            p[r] = fmaf(H, lw, p[r]);
        }
    }
#pragma unroll
    for (int r = 0; r < 4; ++r) {
        float v = p[r];
        v += __shfl_xor(v, 1);
        v += __shfl_xor(v, 2);
        v += __shfl_xor(v, 4);
        v += __shfl_xor(v, 8);
        if (hq == 0) {
            int n = nb + ng * 4 + r;
            if (n < N) out[n] = v + lb;
        }
    }
}

extern "C" void kernel_launch(void* const* d_in, const int* in_sizes, int n_in,
                              void* d_out, int out_size, void* d_ws, size_t ws_size,
                              hipStream_t stream) {
    const float* x   = (const float*)d_in[0];
    const int*   ei  = (const int*)d_in[1];
    const float* ew  = (const float*)d_in[2];
    const float* Wx  = (const float*)d_in[3];
    const float* bx  = (const float*)d_in[4];
    // d_in[5] = Wh (unused: zero initial state)
    const float* bh  = (const float*)d_in[6];
    const float* wcp = (const float*)d_in[7];
    const float* bg  = (const float*)d_in[8];
    const float* lw  = (const float*)d_in[9];
    const float* lb  = (const float*)d_in[10];
    float* out = (float*)d_out;

    const int N  = in_sizes[0] / 32;
    const int nE = in_sizes[2];
    const int* src = ei;
    const int* dst = ei + nE;

    char* ws = (char*)d_ws;
    size_t off = 0;
    float* dinv    = (float*)(ws + off); off += (size_t)N * 4;
    int*   cnt     = (int*)(ws + off);   off += (size_t)N * 4;
    int*   rowptr  = (int*)(ws + off);   off += (size_t)N * 4;
    int*   partials= (int*)(ws + off);   off += 1024 * 4;
    short* P       = (short*)(ws + off); off += 12 * 4 * 64 * 8 * 2;
    int2*  entries = (int2*)(ws + off);  off += (size_t)nE * 8;
    float* degPart = (float*)(ws + off); off += (size_t)NCH * N * 4;
    int*   cntPart = (int*)(ws + off);   off += (size_t)NCH * N * 4;
    short* xbuf    = (short*)(ws + off); off += (size_t)N * 32 * 2;
    short* Tx1b    = (short*)(ws + off); off += (size_t)N * 32 * 2;
    short* Tx2b    = (short*)(ws + off); off += (size_t)N * 32 * 2;

    const int nb = (N + NT - 1) / NT;
    const int nRangeH = (N + RSH - 1) / RSH;
    const int nRangeF = (N + RSF - 1) / RSF;

    k_hist<<<nRangeH * NCH, 1024, 0, stream>>>(src, dst, ew, degPart, cntPart, nE, N);
    k_prepack_xb<<<(12 * 4 * 64 + N * 8 + NT - 1) / NT, NT, 0, stream>>>(Wx, P, x, xbuf, N * 8);
    k_reduce_scanA<<<nb, NT, 0, stream>>>(degPart, cntPart, dinv, cnt, rowptr,
                                          partials, N);
    k_scanB<<<1, 1024, 0, stream>>>(partials, nb);
    k_scanC_off<<<nb, NT, 0, stream>>>(rowptr, partials, cntPart, N);
    k_fill2<<<nRangeF * NCH, 1024, 0, stream>>>(src, dst, ew, dinv, cntPart,
                                                entries, nE, N);

    const int gb = (N * 8 + NT - 1) / NT;
    k_gather_bf<<<gb, NT, 0, stream>>>((const unsigned short*)xbuf, nullptr,
                                       Tx1b, rowptr, cnt, entries, 1.f, N);
    k_gather_bf<<<gb, NT, 0, stream>>>((const unsigned short*)Tx1b,
                                       (const unsigned short*)xbuf,
                                       Tx2b, rowptr, cnt, entries, 2.f, N);

    const int fb = (N + 63) / 64;
    k_final_g3<<<fb, NT, 0, stream>>>(xbuf, Tx1b, (const unsigned short*)Tx2b, P,
                                      rowptr, cnt, entries, bx, bh, wcp, bg,
                                      lw, lb, out, N);
}

// Round 11
// 103.400 us; speedup vs baseline: 2.1916x; 1.1442x over previous
//
#include <hip/hip_runtime.h>
#include <math.h>

// GConvLSTM single step from zero state + linear head.
// H=C=0 initially => cheb_conv(H)=bh[g], F-gate irrelevant.
//   I = sigmoid(chebX_0 + b*), T = tanh(chebX_2 + b*), C = I*T,
//   O = sigmoid(chebX_3 + b* + wc2*C), out = (O*tanh(C)) @ lin_w + lin_b
//
// R2 pull-CSR; R3 hw transcendentals; R7 zero global atomics;
// R8 bf16 MFMA; R9 bf16 recursion; R10 fused gather3 into final.
// R11: NCH=64 (full-CU edge scans: hist 192 blocks, fill 256 blocks);
//      u16-packed cnt histogram (RSH=20480 -> 3 ranges, half cnt traffic);
//      scanB folded into scan_off (per-block prefix reduce);
//      prepack+xb fused into hist kernel as extra blocks. 7 launches.

#define NT 256
#define NCH 64      // edge chunks
#define RSH 20480   // hist range: 20480*(4+2)B = 120KB LDS
#define RSF 16384   // fill range: 64KB LDS

typedef __attribute__((ext_vector_type(8))) short short8v;
typedef __attribute__((ext_vector_type(8))) unsigned short ushort8v;
typedef __attribute__((ext_vector_type(4))) float f32x4;

__device__ __forceinline__ short f2bf(float f) {
    unsigned u = __float_as_uint(f);
    u += 0x7FFFu + ((u >> 16) & 1u);   // round-to-nearest-even
    return (short)(u >> 16);
}
__device__ __forceinline__ float bf2f(unsigned short b) {
    return __uint_as_float((unsigned)b << 16);
}

// role A (bid < histB): per-(range,chunk) LDS histogram, deg f32 + cnt u16-packed.
// role B (bid >= histB): prepack W fragments + x->bf16.
__global__ __launch_bounds__(1024)
void k_front(const int* __restrict__ src, const int* __restrict__ dst,
             const float* __restrict__ w, float* __restrict__ degPart,
             unsigned short* __restrict__ cntPart,
             const float* __restrict__ Wx, short* __restrict__ P,
             const float* __restrict__ x, short* __restrict__ xb,
             int nE, int N, int histB, int n4) {
    __shared__ float    s_deg[RSH];
    __shared__ unsigned s_cnt2[RSH / 2];
    const int bid = blockIdx.x;
    if (bid >= histB) {
        int idx = (bid - histB) * 1024 + (int)threadIdx.x;
        if (idx < 12 * 4 * 64) {
            // P[(nt*4+kt)*64+lane][j] = Wx[gate][kt][(lane>>4)*8+j][(nt&3)*16+(lane&15)]
            int lane = idx & 63;
            int kt = (idx >> 6) & 3;
            int nt = idx >> 8;
            int gate = (nt < 4) ? 0 : (nt < 8) ? 2 : 3;
            int h = (nt & 3) * 16 + (lane & 15);
            int fb = (lane >> 4) * 8;
            short8v v;
#pragma unroll
            for (int j = 0; j < 8; ++j)
                v[j] = f2bf(Wx[((size_t)(gate * 4 + kt) * 32 + fb + j) * 64 + h]);
            *(reinterpret_cast<short8v*>(P) + idx) = v;
            return;
        }
        int i = idx - 12 * 4 * 64;
        if (i >= n4) return;
        const float4 v = *reinterpret_cast<const float4*>(x + (size_t)i * 4);
        short4 rb;
        rb.x = f2bf(v.x); rb.y = f2bf(v.y); rb.z = f2bf(v.z); rb.w = f2bf(v.w);
        *reinterpret_cast<short4*>(xb + (size_t)i * 4) = rb;
        return;
    }
    const int r = bid / NCH, b = bid % NCH;
    const int base = r * RSH;
    for (int i = threadIdx.x; i < RSH; i += 1024) s_deg[i] = 0.f;
    for (int i = threadIdx.x; i < RSH / 2; i += 1024) s_cnt2[i] = 0u;
    __syncthreads();
    const int chunk = (nE + NCH - 1) / NCH;
    const int e0 = b * chunk, e1 = min(e0 + chunk, nE);
    for (int e = e0 + (int)threadIdx.x; e < e1; e += 1024) {
        int s = src[e], d = dst[e];
        unsigned so = (unsigned)(s - base), dof = (unsigned)(d - base);
        if (so < RSH) atomicAdd(&s_deg[so], w[e]);
        if (dof < RSH) atomicAdd(&s_cnt2[dof >> 1], 1u << ((dof & 1) * 16));
    }
    __syncthreads();
    const int lim = min(RSH, N - base);
    for (int i = threadIdx.x; i < lim; i += 1024)
        degPart[(size_t)b * N + base + i] = s_deg[i];
    // cnt flush as u32 pairs ((b*N+base) is even when N is even)
    unsigned* cp32 = reinterpret_cast<unsigned*>(cntPart + (size_t)b * N + base);
    const int pairs = lim >> 1;
    for (int i = threadIdx.x; i < pairs; i += 1024) cp32[i] = s_cnt2[i];
    if ((lim & 1) && threadIdx.x == 0)
        cntPart[(size_t)b * N + base + lim - 1] =
            (unsigned short)(s_cnt2[lim >> 1] & 0xFFFFu);
}

// reduce partials -> dinv/cnt + block-local exclusive scan (512 nodes/block)
__global__ __launch_bounds__(NT)
void k_reduce_scanA(const float* __restrict__ degPart,
                    const unsigned short* __restrict__ cntPart,
                    float* __restrict__ dinv, int* __restrict__ cnt,
                    int* __restrict__ rowptr, int* __restrict__ partials, int N) {
    __shared__ int s[NT];
    const int t = threadIdx.x;
    const int n0 = blockIdx.x * (NT * 2) + t * 2;
    float d0 = 0.f, d1 = 0.f;
    int c0 = 0, c1 = 0;
    if (n0 < N) {
#pragma unroll 8
        for (int b = 0; b < NCH; ++b) {
            const float2 dv = *reinterpret_cast<const float2*>(degPart + (size_t)b * N + n0);
            d0 += dv.x; d1 += dv.y;
            unsigned cc = *reinterpret_cast<const unsigned*>(cntPart + (size_t)b * N + n0);
            c0 += (int)(cc & 0xFFFFu); c1 += (int)(cc >> 16);
        }
        dinv[n0] = d0 > 0.f ? rsqrtf(d0) : 0.f;
        cnt[n0] = c0;
        if (n0 + 1 < N) {
            dinv[n0 + 1] = d1 > 0.f ? rsqrtf(d1) : 0.f;
            cnt[n0 + 1] = c1;
        } else c1 = 0;
    }
    int cs = c0 + c1;
    s[t] = cs;
    __syncthreads();
    for (int off = 1; off < NT; off <<= 1) {
        int u = (t >= off) ? s[t - off] : 0;
        __syncthreads();
        s[t] += u;
        __syncthreads();
    }
    int ex = s[t] - cs;
    if (n0 < N) {
        rowptr[n0] = ex;
        if (n0 + 1 < N) rowptr[n0 + 1] = ex + c0;
    }
    if (t == NT - 1) partials[blockIdx.x] = s[t];
}

// per-block prefix over partials (folded scanB), globalize rowptr,
// chunk-axis exclusive scan -> per-chunk slot offsets
__global__ __launch_bounds__(NT)
void k_scan_off(int* __restrict__ rowptr, const int* __restrict__ partials, int nb2,
                const unsigned short* __restrict__ cntPart, int* __restrict__ offs,
                int N) {
    __shared__ int sp[NT];
    const int t = threadIdx.x;
    int v = (t < (int)blockIdx.x && t < nb2) ? partials[t] : 0;
    sp[t] = v;
    __syncthreads();
    for (int off = NT / 2; off > 0; off >>= 1) {
        if (t < off) sp[t] += sp[t + off];
        __syncthreads();
    }
    const int prefix = sp[0];
    const int n0 = blockIdx.x * (NT * 2) + t * 2;
    if (n0 >= N) return;
    const bool has1 = (n0 + 1) < N;
    int s0 = rowptr[n0] + prefix;
    int s1 = has1 ? rowptr[n0 + 1] + prefix : 0;
    rowptr[n0] = s0;
    if (has1) rowptr[n0 + 1] = s1;
#pragma unroll 8
    for (int b = 0; b < NCH; ++b) {
        unsigned cc = *reinterpret_cast<const unsigned*>(cntPart + (size_t)b * N + n0);
        if (has1) {
            *reinterpret_cast<int2*>(offs + (size_t)b * N + n0) = make_int2(s0, s1);
        } else {
            offs[(size_t)b * N + n0] = s0;
        }
        s0 += (int)(cc & 0xFFFFu);
        s1 += (int)(cc >> 16);
    }
}

// counting-sort fill: LDS cursor seeded from per-chunk offsets; no global atomics
__global__ __launch_bounds__(1024)
void k_fill2(const int* __restrict__ src, const int* __restrict__ dst,
             const float* __restrict__ w, const float* __restrict__ dinv,
             const int* __restrict__ offs, int2* __restrict__ entries,
             int nE, int N) {
    __shared__ int s_cur[RSF];
    const int r = blockIdx.x / NCH, b = blockIdx.x % NCH;
    const int base = r * RSF;
    const int lim = min(RSF, N - base);
    for (int i = threadIdx.x; i < lim; i += 1024)
        s_cur[i] = offs[(size_t)b * N + base + i];
    __syncthreads();
    const int chunk = (nE + NCH - 1) / NCH;
    const int e0 = b * chunk, e1 = min(e0 + chunk, nE);
    for (int e = e0 + (int)threadIdx.x; e < e1; e += 1024) {
        int d = dst[e];
        unsigned dof = (unsigned)(d - base);
        if (dof < RSF) {
            int s = src[e];
            float nv = -dinv[s] * w[e] * dinv[d];
            int pos = atomicAdd(&s_cur[dof], 1);
            entries[pos] = make_int2(s, __float_as_int(nv));
        }
    }
}

__device__ __forceinline__ void bf8_fma(float* acc, ushort8v v, float s) {
#pragma unroll
    for (int j = 0; j < 8; ++j)
        acc[j] = fmaf(s, bf2f(v[j]), acc[j]);
}

// bf16-table gather, f32 accumulate, bf16 out. 8 threads/node:
// tq = idx&3 (8-feature slice), half = (idx>>2)&1 (entry parity).
__global__ __launch_bounds__(256)
void k_gather_bf(const unsigned short* __restrict__ tb,
                 const unsigned short* __restrict__ subb,
                 short* __restrict__ outb,
                 const int* __restrict__ rowptr, const int* __restrict__ cnt,
                 const int2* __restrict__ entries, float scale, int N) {
    int idx = blockIdx.x * blockDim.x + threadIdx.x;
    if (idx >= N * 8) return;
    int n = idx >> 3, tq = idx & 3, half = (idx >> 2) & 1;
    int beg = rowptr[n], end = beg + cnt[n];
    float acc0[8] = {0, 0, 0, 0, 0, 0, 0, 0};
    float acc1[8] = {0, 0, 0, 0, 0, 0, 0, 0};
    int i = beg + half;
    for (; i + 6 < end; i += 8) {
        int2 e0 = entries[i];
        int2 e1 = entries[i + 2];
        int2 e2 = entries[i + 4];
        int2 e3 = entries[i + 6];
        ushort8v v0 = *reinterpret_cast<const ushort8v*>(tb + (size_t)e0.x * 32 + tq * 8);
        ushort8v v1 = *reinterpret_cast<const ushort8v*>(tb + (size_t)e1.x * 32 + tq * 8);
        ushort8v v2 = *reinterpret_cast<const ushort8v*>(tb + (size_t)e2.x * 32 + tq * 8);
        ushort8v v3 = *reinterpret_cast<const ushort8v*>(tb + (size_t)e3.x * 32 + tq * 8);
        bf8_fma(acc0, v0, __int_as_float(e0.y));
        bf8_fma(acc1, v1, __int_as_float(e1.y));
        bf8_fma(acc0, v2, __int_as_float(e2.y));
        bf8_fma(acc1, v3, __int_as_float(e3.y));
    }
    for (; i < end; i += 2) {
        int2 e0 = entries[i];
        ushort8v v0 = *reinterpret_cast<const ushort8v*>(tb + (size_t)e0.x * 32 + tq * 8);
        bf8_fma(acc0, v0, __int_as_float(e0.y));
    }
    float r[8];
#pragma unroll
    for (int j = 0; j < 8; ++j) {
        r[j] = acc0[j] + acc1[j];
        r[j] += __shfl_xor(r[j], 4);   // combine entry-parity halves
    }
    if (!half) {
        if (subb) {
            ushort8v sv = *reinterpret_cast<const ushort8v*>(subb + (size_t)n * 32 + tq * 8);
#pragma unroll
            for (int j = 0; j < 8; ++j) r[j] = fmaf(scale, r[j], -bf2f(sv[j]));
        } else {
#pragma unroll
            for (int j = 0; j < 8; ++j) r[j] *= scale;
        }
        short8v rb;
#pragma unroll
        for (int j = 0; j < 8; ++j) rb[j] = f2bf(r[j]);
        *reinterpret_cast<short8v*>(outb + (size_t)n * 32 + tq * 8) = rb;
    }
}

__device__ __forceinline__ float sigf(float x) {
    return __builtin_amdgcn_rcpf(1.f + __builtin_amdgcn_exp2f(-1.4426950408889634f * x));
}
__device__ __forceinline__ float tanhf_fast(float x) {
    float e = __builtin_amdgcn_exp2f(2.8853900817779268f * x);
    return 1.f - 2.f * __builtin_amdgcn_rcpf(e + 1.f);
}

// fused gather3 + MFMA gates GEMM + LSTM pointwise + linear head.
__global__ __launch_bounds__(256)
void k_final_g3(const short* __restrict__ xb, const short* __restrict__ t1b,
                const unsigned short* __restrict__ t2b,
                const short* __restrict__ P,
                const int* __restrict__ rowptr, const int* __restrict__ cnt,
                const int2* __restrict__ entries,
                const float* __restrict__ bx, const float* __restrict__ bh,
                const float* __restrict__ wc, const float* __restrict__ bg,
                const float* __restrict__ lin_w, const float* __restrict__ lin_b,
                float* __restrict__ out, int N) {
    const int wave = threadIdx.x >> 6, lane = threadIdx.x & 63;
    const int nb = blockIdx.x * 64 + wave * 16;
    const int rc = min(nb + (lane & 15), N - 1);
    const int ko = (lane >> 4) * 8;

    int beg = rowptr[rc], end = beg + cnt[rc];
    float acc0[8] = {0, 0, 0, 0, 0, 0, 0, 0};
    float acc1[8] = {0, 0, 0, 0, 0, 0, 0, 0};
    int i = beg;
    for (; i + 3 < end; i += 4) {
        int2 e0 = entries[i];
        int2 e1 = entries[i + 1];
        int2 e2 = entries[i + 2];
        int2 e3 = entries[i + 3];
        ushort8v v0 = *reinterpret_cast<const ushort8v*>(t2b + (size_t)e0.x * 32 + ko);
        ushort8v v1 = *reinterpret_cast<const ushort8v*>(t2b + (size_t)e1.x * 32 + ko);
        ushort8v v2 = *reinterpret_cast<const ushort8v*>(t2b + (size_t)e2.x * 32 + ko);
        ushort8v v3 = *reinterpret_cast<const ushort8v*>(t2b + (size_t)e3.x * 32 + ko);
        bf8_fma(acc0, v0, __int_as_float(e0.y));
        bf8_fma(acc1, v1, __int_as_float(e1.y));
        bf8_fma(acc0, v2, __int_as_float(e2.y));
        bf8_fma(acc1, v3, __int_as_float(e3.y));
    }
    for (; i < end; ++i) {
        int2 e0 = entries[i];
        ushort8v v0 = *reinterpret_cast<const ushort8v*>(t2b + (size_t)e0.x * 32 + ko);
        bf8_fma(acc0, v0, __int_as_float(e0.y));
    }

    short8v A0 = *reinterpret_cast<const short8v*>(xb  + (size_t)rc * 32 + ko);
    short8v A1 = *reinterpret_cast<const short8v*>(t1b + (size_t)rc * 32 + ko);
    short8v A2 = *reinterpret_cast<const short8v*>(
        reinterpret_cast<const short*>(t2b) + (size_t)rc * 32 + ko);
    short8v A3;
#pragma unroll
    for (int j = 0; j < 8; ++j)   // Tx3 = 2*prop(Tx2) - Tx1
        A3[j] = f2bf(2.f * (acc0[j] + acc1[j]) - bf2f((unsigned short)A1[j]));

    const short8v* Pv = reinterpret_cast<const short8v*>(P);
    f32x4 acc[12];
#pragma unroll
    for (int nt = 0; nt < 12; ++nt) {
        const short8v* Pb = Pv + (size_t)nt * 4 * 64 + lane;
        f32x4 a = {0.f, 0.f, 0.f, 0.f};
        a = __builtin_amdgcn_mfma_f32_16x16x32_bf16(A0, Pb[0],   a, 0, 0, 0);
        a = __builtin_amdgcn_mfma_f32_16x16x32_bf16(A1, Pb[64],  a, 0, 0, 0);
        a = __builtin_amdgcn_mfma_f32_16x16x32_bf16(A2, Pb[128], a, 0, 0, 0);
        a = __builtin_amdgcn_mfma_f32_16x16x32_bf16(A3, Pb[192], a, 0, 0, 0);
        acc[nt] = a;
    }

    const int hq = lane & 15;
    const int ng = lane >> 4;
    const float lb = lin_b[0];
    float p[4] = {0.f, 0.f, 0.f, 0.f};
#pragma unroll
    for (int ht = 0; ht < 4; ++ht) {
        int h = ht * 16 + hq;
        float bI = bx[h] + bh[h] + bg[h];
        float bC = bx[128 + h] + bh[128 + h] + bg[128 + h];
        float bO = bx[192 + h] + bh[192 + h] + bg[192 + h];
        float w2 = wc[128 + h];
        float lw = lin_w[h];
#pragma unroll
        for (int r = 0; r < 4; ++r) {
            float I = sigf(acc[ht][r] + bI);
            float T = tanhf_fast(acc[4 + ht][r] + bC);
            float C = I * T;
            float O = sigf(acc[8 + ht][r] + bO + w2 * C);
            float H = O * tanhf_fast(C);
            p[r] = fmaf(H, lw, p[r]);
        }
    }
#pragma unroll
    for (int r = 0; r < 4; ++r) {
        float v = p[r];
        v += __shfl_xor(v, 1);
        v += __shfl_xor(v, 2);
        v += __shfl_xor(v, 4);
        v += __shfl_xor(v, 8);
        if (hq == 0) {
            int n = nb + ng * 4 + r;
            if (n < N) out[n] = v + lb;
        }
    }
}

extern "C" void kernel_launch(void* const* d_in, const int* in_sizes, int n_in,
                              void* d_out, int out_size, void* d_ws, size_t ws_size,
                              hipStream_t stream) {
    const float* x   = (const float*)d_in[0];
    const int*   ei  = (const int*)d_in[1];
    const float* ew  = (const float*)d_in[2];
    const float* Wx  = (const float*)d_in[3];
    const float* bx  = (const float*)d_in[4];
    // d_in[5] = Wh (unused: zero initial state)
    const float* bh  = (const float*)d_in[6];
    const float* wcp = (const float*)d_in[7];
    const float* bg  = (const float*)d_in[8];
    const float* lw  = (const float*)d_in[9];
    const float* lb  = (const float*)d_in[10];
    float* out = (float*)d_out;

    const int N  = in_sizes[0] / 32;
    const int nE = in_sizes[2];
    const int* src = ei;
    const int* dst = ei + nE;

    char* ws = (char*)d_ws;
    size_t off = 0;
    float* dinv    = (float*)(ws + off); off += (size_t)N * 4;
    int*   cnt     = (int*)(ws + off);   off += (size_t)N * 4;
    int*   rowptr  = (int*)(ws + off);   off += (size_t)N * 4;
    int*   partials= (int*)(ws + off);   off += 1024 * 4;
    short* P       = (short*)(ws + off); off += 12 * 4 * 64 * 8 * 2;
    int2*  entries = (int2*)(ws + off);  off += (size_t)nE * 8;
    float* degPart = (float*)(ws + off); off += (size_t)NCH * N * 4;  // aliased as offs later
    unsigned short* cntPart = (unsigned short*)(ws + off); off += (size_t)NCH * N * 2;
    short* xbuf    = (short*)(ws + off); off += (size_t)N * 32 * 2;
    short* Tx1b    = (short*)(ws + off); off += (size_t)N * 32 * 2;
    short* Tx2b    = (short*)(ws + off); off += (size_t)N * 32 * 2;

    int* offs = (int*)degPart;  // degPart dead after k_reduce_scanA

    const int nRangeH = (N + RSH - 1) / RSH;
    const int nRangeF = (N + RSF - 1) / RSF;
    const int histB = nRangeH * NCH;
    const int n4 = N * 8;
    const int xbB = (12 * 4 * 64 + n4 + 1023) / 1024;
    const int nb2 = (N + NT * 2 - 1) / (NT * 2);

    k_front<<<histB + xbB, 1024, 0, stream>>>(src, dst, ew, degPart, cntPart,
                                              Wx, P, x, xbuf, nE, N, histB, n4);
    k_reduce_scanA<<<nb2, NT, 0, stream>>>(degPart, cntPart, dinv, cnt, rowptr,
                                           partials, N);
    k_scan_off<<<nb2, NT, 0, stream>>>(rowptr, partials, nb2, cntPart, offs, N);
    k_fill2<<<nRangeF * NCH, 1024, 0, stream>>>(src, dst, ew, dinv, offs,
                                                entries, nE, N);

    const int gb = (N * 8 + NT - 1) / NT;
    k_gather_bf<<<gb, NT, 0, stream>>>((const unsigned short*)xbuf, nullptr,
                                       Tx1b, rowptr, cnt, entries, 1.f, N);
    k_gather_bf<<<gb, NT, 0, stream>>>((const unsigned short*)Tx1b,
                                       (const unsigned short*)xbuf,
                                       Tx2b, rowptr, cnt, entries, 2.f, N);

    const int fb = (N + 63) / 64;
    k_final_g3<<<fb, NT, 0, stream>>>(xbuf, Tx1b, (const unsigned short*)Tx2b, P,
                                      rowptr, cnt, entries, bx, bh, wcp, bg,
                                      lw, lb, out, N);
}

// Round 12
// 103.173 us; speedup vs baseline: 2.1964x; 1.0022x over previous
//
#include <hip/hip_runtime.h>
#include <math.h>

// GConvLSTM single step from zero state + linear head.
// H=C=0 initially => cheb_conv(H)=bh[g], F-gate irrelevant.
//   I = sigmoid(chebX_0 + b*), T = tanh(chebX_2 + b*), C = I*T,
//   O = sigmoid(chebX_3 + b* + wc2*C), out = (O*tanh(C)) @ lin_w + lin_b
//
// R2 pull-CSR; R3 hw transcendentals; R7 zero global atomics;
// R8 bf16 MFMA; R9 bf16 recursion; R10 fused gather3; R11 full-CU scans.
// R12: RSF=20480 (3 fill passes); reduce_scanA+scan_off merged via
//      in-kernel atomic barrier (98 co-resident blocks, LDS-cached cnt);
//      gather quarter-split (16 thr/node, chain 4).

#define NT 256
#define NCH 64      // edge chunks
#define RSH 20480   // hist range: 20480*(4+2)B = 120KB LDS
#define RSF 20480   // fill range: 80KB LDS

typedef __attribute__((ext_vector_type(8))) short short8v;
typedef __attribute__((ext_vector_type(8))) unsigned short ushort8v;
typedef __attribute__((ext_vector_type(4))) float f32x4;

__device__ __forceinline__ short f2bf(float f) {
    unsigned u = __float_as_uint(f);
    u += 0x7FFFu + ((u >> 16) & 1u);   // round-to-nearest-even
    return (short)(u >> 16);
}
__device__ __forceinline__ float bf2f(unsigned short b) {
    return __uint_as_float((unsigned)b << 16);
}

// role A (bid < histB): per-(range,chunk) LDS histogram, deg f32 + cnt u16-packed.
// role B (bid >= histB): prepack W fragments + x->bf16.
__global__ __launch_bounds__(1024)
void k_front(const int* __restrict__ src, const int* __restrict__ dst,
             const float* __restrict__ w, float* __restrict__ degPart,
             unsigned short* __restrict__ cntPart,
             const float* __restrict__ Wx, short* __restrict__ P,
             const float* __restrict__ x, short* __restrict__ xb,
             int nE, int N, int histB, int n4) {
    __shared__ float    s_deg[RSH];
    __shared__ unsigned s_cnt2[RSH / 2];
    const int bid = blockIdx.x;
    if (bid >= histB) {
        int idx = (bid - histB) * 1024 + (int)threadIdx.x;
        if (idx < 12 * 4 * 64) {
            int lane = idx & 63;
            int kt = (idx >> 6) & 3;
            int nt = idx >> 8;
            int gate = (nt < 4) ? 0 : (nt < 8) ? 2 : 3;
            int h = (nt & 3) * 16 + (lane & 15);
            int fb = (lane >> 4) * 8;
            short8v v;
#pragma unroll
            for (int j = 0; j < 8; ++j)
                v[j] = f2bf(Wx[((size_t)(gate * 4 + kt) * 32 + fb + j) * 64 + h]);
            *(reinterpret_cast<short8v*>(P) + idx) = v;
            return;
        }
        int i = idx - 12 * 4 * 64;
        if (i >= n4) return;
        const float4 v = *reinterpret_cast<const float4*>(x + (size_t)i * 4);
        short4 rb;
        rb.x = f2bf(v.x); rb.y = f2bf(v.y); rb.z = f2bf(v.z); rb.w = f2bf(v.w);
        *reinterpret_cast<short4*>(xb + (size_t)i * 4) = rb;
        return;
    }
    const int r = bid / NCH, b = bid % NCH;
    const int base = r * RSH;
    for (int i = threadIdx.x; i < RSH; i += 1024) s_deg[i] = 0.f;
    for (int i = threadIdx.x; i < RSH / 2; i += 1024) s_cnt2[i] = 0u;
    __syncthreads();
    const int chunk = (nE + NCH - 1) / NCH;
    const int e0 = b * chunk, e1 = min(e0 + chunk, nE);
    for (int e = e0 + (int)threadIdx.x; e < e1; e += 1024) {
        int s = src[e], d = dst[e];
        unsigned so = (unsigned)(s - base), dof = (unsigned)(d - base);
        if (so < RSH) atomicAdd(&s_deg[so], w[e]);
        if (dof < RSH) atomicAdd(&s_cnt2[dof >> 1], 1u << ((dof & 1) * 16));
    }
    __syncthreads();
    const int lim = min(RSH, N - base);
    for (int i = threadIdx.x; i < lim; i += 1024)
        degPart[(size_t)b * N + base + i] = s_deg[i];
    unsigned* cp32 = reinterpret_cast<unsigned*>(cntPart + (size_t)b * N + base);
    const int pairs = lim >> 1;
    for (int i = threadIdx.x; i < pairs; i += 1024) cp32[i] = s_cnt2[i];
    if ((lim & 1) && threadIdx.x == 0)
        cntPart[(size_t)b * N + base + lim - 1] =
            (unsigned short)(s_cnt2[lim >> 1] & 0xFFFFu);
}

// merged: reduce partials -> dinv/cnt, block scan, ATOMIC BARRIER (98 blocks
// co-resident on 256 CUs), per-block partial prefix, rowptr + per-chunk offs
// (from LDS-cached cnt -- no cntPart re-read).
__global__ __launch_bounds__(NT)
void k_scan_merged(const float* __restrict__ degPart,
                   const unsigned short* __restrict__ cntPart,
                   float* __restrict__ dinv, int* __restrict__ cnt,
                   int* __restrict__ rowptr, int* __restrict__ partials,
                   int* __restrict__ flag, int* __restrict__ offs, int N) {
    __shared__ unsigned s_c[NCH * NT];   // 64KB: per-thread 2-node packed cnt
    __shared__ int sp[NT];
    const int t = threadIdx.x;
    const int n0 = blockIdx.x * (NT * 2) + t * 2;
    float d0 = 0.f, d1 = 0.f;
    int c0 = 0, c1 = 0;
    if (n0 < N) {
#pragma unroll 8
        for (int b = 0; b < NCH; ++b) {
            const float2 dv = *reinterpret_cast<const float2*>(degPart + (size_t)b * N + n0);
            d0 += dv.x; d1 += dv.y;
            unsigned cc = *reinterpret_cast<const unsigned*>(cntPart + (size_t)b * N + n0);
            s_c[b * NT + t] = cc;
            c0 += (int)(cc & 0xFFFFu); c1 += (int)(cc >> 16);
        }
        dinv[n0] = d0 > 0.f ? rsqrtf(d0) : 0.f;
        cnt[n0] = c0;
        if (n0 + 1 < N) {
            dinv[n0 + 1] = d1 > 0.f ? rsqrtf(d1) : 0.f;
            cnt[n0 + 1] = c1;
        } else c1 = 0;
    }
    int cs = c0 + c1;
    sp[t] = cs;
    __syncthreads();
    for (int off = 1; off < NT; off <<= 1) {
        int u = (t >= off) ? sp[t - off] : 0;
        __syncthreads();
        sp[t] += u;
        __syncthreads();
    }
    const int ex = sp[t] - cs;
    const int total = sp[NT - 1];
    __syncthreads();
    // publish partial (device-scope release) + barrier on flag
    if (t == 0) {
        __hip_atomic_store(&partials[blockIdx.x], total, __ATOMIC_RELEASE,
                           __HIP_MEMORY_SCOPE_AGENT);
        atomicAdd(flag, 1);
        while (__hip_atomic_load(flag, __ATOMIC_ACQUIRE,
                                 __HIP_MEMORY_SCOPE_AGENT) < (int)gridDim.x)
            __builtin_amdgcn_s_sleep(1);
    }
    __syncthreads();
    // per-block prefix over preceding partials (device-scope loads)
    int v = (t < (int)blockIdx.x)
                ? __hip_atomic_load(&partials[t], __ATOMIC_ACQUIRE,
                                    __HIP_MEMORY_SCOPE_AGENT)
                : 0;
    sp[t] = v;
    __syncthreads();
    for (int off = NT / 2; off > 0; off >>= 1) {
        if (t < off) sp[t] += sp[t + off];
        __syncthreads();
    }
    const int prefix = sp[0];
    if (n0 >= N) return;
    const bool has1 = (n0 + 1) < N;
    int s0 = ex + prefix;
    int s1 = has1 ? ex + c0 + prefix : 0;
    rowptr[n0] = s0;
    if (has1) rowptr[n0 + 1] = s1;
#pragma unroll 8
    for (int b = 0; b < NCH; ++b) {
        unsigned cc = s_c[b * NT + t];
        if (has1) {
            *reinterpret_cast<int2*>(offs + (size_t)b * N + n0) = make_int2(s0, s1);
        } else {
            offs[(size_t)b * N + n0] = s0;
        }
        s0 += (int)(cc & 0xFFFFu);
        s1 += (int)(cc >> 16);
    }
}

// counting-sort fill: LDS cursor seeded from per-chunk offsets; no global atomics
__global__ __launch_bounds__(1024)
void k_fill2(const int* __restrict__ src, const int* __restrict__ dst,
             const float* __restrict__ w, const float* __restrict__ dinv,
             const int* __restrict__ offs, int2* __restrict__ entries,
             int nE, int N) {
    __shared__ int s_cur[RSF];
    const int r = blockIdx.x / NCH, b = blockIdx.x % NCH;
    const int base = r * RSF;
    const int lim = min(RSF, N - base);
    for (int i = threadIdx.x; i < lim; i += 1024)
        s_cur[i] = offs[(size_t)b * N + base + i];
    __syncthreads();
    const int chunk = (nE + NCH - 1) / NCH;
    const int e0 = b * chunk, e1 = min(e0 + chunk, nE);
    for (int e = e0 + (int)threadIdx.x; e < e1; e += 1024) {
        int d = dst[e];
        unsigned dof = (unsigned)(d - base);
        if (dof < RSF) {
            int s = src[e];
            float nv = -dinv[s] * w[e] * dinv[d];
            int pos = atomicAdd(&s_cur[dof], 1);
            entries[pos] = make_int2(s, __float_as_int(nv));
        }
    }
}

__device__ __forceinline__ void bf8_fma(float* acc, ushort8v v, float s) {
#pragma unroll
    for (int j = 0; j < 8; ++j)
        acc[j] = fmaf(s, bf2f(v[j]), acc[j]);
}

// bf16-table gather, f32 accumulate, bf16 out. 16 threads/node:
// tq = idx&3 (8-feature slice), qr = (idx>>2)&3 (entry quarter, stride 4).
// Chain ~cnt/4; combine via shfl_xor(4) + shfl_xor(8).
__global__ __launch_bounds__(256)
void k_gather_bf(const unsigned short* __restrict__ tb,
                 const unsigned short* __restrict__ subb,
                 short* __restrict__ outb,
                 const int* __restrict__ rowptr, const int* __restrict__ cnt,
                 const int2* __restrict__ entries, float scale, int N) {
    int idx = blockIdx.x * blockDim.x + threadIdx.x;
    if (idx >= N * 16) return;
    int n = idx >> 4, tq = idx & 3, qr = (idx >> 2) & 3;
    int beg = rowptr[n], end = beg + cnt[n];
    float acc0[8] = {0, 0, 0, 0, 0, 0, 0, 0};
    float acc1[8] = {0, 0, 0, 0, 0, 0, 0, 0};
    int i = beg + qr;
    for (; i + 12 < end; i += 16) {
        int2 e0 = entries[i];
        int2 e1 = entries[i + 4];
        int2 e2 = entries[i + 8];
        int2 e3 = entries[i + 12];
        ushort8v v0 = *reinterpret_cast<const ushort8v*>(tb + (size_t)e0.x * 32 + tq * 8);
        ushort8v v1 = *reinterpret_cast<const ushort8v*>(tb + (size_t)e1.x * 32 + tq * 8);
        ushort8v v2 = *reinterpret_cast<const ushort8v*>(tb + (size_t)e2.x * 32 + tq * 8);
        ushort8v v3 = *reinterpret_cast<const ushort8v*>(tb + (size_t)e3.x * 32 + tq * 8);
        bf8_fma(acc0, v0, __int_as_float(e0.y));
        bf8_fma(acc1, v1, __int_as_float(e1.y));
        bf8_fma(acc0, v2, __int_as_float(e2.y));
        bf8_fma(acc1, v3, __int_as_float(e3.y));
    }
    for (; i < end; i += 4) {
        int2 e0 = entries[i];
        ushort8v v0 = *reinterpret_cast<const ushort8v*>(tb + (size_t)e0.x * 32 + tq * 8);
        bf8_fma(acc0, v0, __int_as_float(e0.y));
    }
    float r[8];
#pragma unroll
    for (int j = 0; j < 8; ++j) {
        r[j] = acc0[j] + acc1[j];
        r[j] += __shfl_xor(r[j], 4);
        r[j] += __shfl_xor(r[j], 8);
    }
    if (qr == 0) {
        if (subb) {
            ushort8v sv = *reinterpret_cast<const ushort8v*>(subb + (size_t)n * 32 + tq * 8);
#pragma unroll
            for (int j = 0; j < 8; ++j) r[j] = fmaf(scale, r[j], -bf2f(sv[j]));
        } else {
#pragma unroll
            for (int j = 0; j < 8; ++j) r[j] *= scale;
        }
        short8v rb;
#pragma unroll
        for (int j = 0; j < 8; ++j) rb[j] = f2bf(r[j]);
        *reinterpret_cast<short8v*>(outb + (size_t)n * 32 + tq * 8) = rb;
    }
}

__device__ __forceinline__ float sigf(float x) {
    return __builtin_amdgcn_rcpf(1.f + __builtin_amdgcn_exp2f(-1.4426950408889634f * x));
}
__device__ __forceinline__ float tanhf_fast(float x) {
    float e = __builtin_amdgcn_exp2f(2.8853900817779268f * x);
    return 1.f - 2.f * __builtin_amdgcn_rcpf(e + 1.f);
}

// fused gather3 + MFMA gates GEMM + LSTM pointwise + linear head.
__global__ __launch_bounds__(256)
void k_final_g3(const short* __restrict__ xb, const short* __restrict__ t1b,
                const unsigned short* __restrict__ t2b,
                const short* __restrict__ P,
                const int* __restrict__ rowptr, const int* __restrict__ cnt,
                const int2* __restrict__ entries,
                const float* __restrict__ bx, const float* __restrict__ bh,
                const float* __restrict__ wc, const float* __restrict__ bg,
                const float* __restrict__ lin_w, const float* __restrict__ lin_b,
                float* __restrict__ out, int N) {
    const int wave = threadIdx.x >> 6, lane = threadIdx.x & 63;
    const int nb = blockIdx.x * 64 + wave * 16;
    const int rc = min(nb + (lane & 15), N - 1);
    const int ko = (lane >> 4) * 8;

    int beg = rowptr[rc], end = beg + cnt[rc];
    float acc0[8] = {0, 0, 0, 0, 0, 0, 0, 0};
    float acc1[8] = {0, 0, 0, 0, 0, 0, 0, 0};
    int i = beg;
    for (; i + 3 < end; i += 4) {
        int2 e0 = entries[i];
        int2 e1 = entries[i + 1];
        int2 e2 = entries[i + 2];
        int2 e3 = entries[i + 3];
        ushort8v v0 = *reinterpret_cast<const ushort8v*>(t2b + (size_t)e0.x * 32 + ko);
        ushort8v v1 = *reinterpret_cast<const ushort8v*>(t2b + (size_t)e1.x * 32 + ko);
        ushort8v v2 = *reinterpret_cast<const ushort8v*>(t2b + (size_t)e2.x * 32 + ko);
        ushort8v v3 = *reinterpret_cast<const ushort8v*>(t2b + (size_t)e3.x * 32 + ko);
        bf8_fma(acc0, v0, __int_as_float(e0.y));
        bf8_fma(acc1, v1, __int_as_float(e1.y));
        bf8_fma(acc0, v2, __int_as_float(e2.y));
        bf8_fma(acc1, v3, __int_as_float(e3.y));
    }
    for (; i < end; ++i) {
        int2 e0 = entries[i];
        ushort8v v0 = *reinterpret_cast<const ushort8v*>(t2b + (size_t)e0.x * 32 + ko);
        bf8_fma(acc0, v0, __int_as_float(e0.y));
    }

    short8v A0 = *reinterpret_cast<const short8v*>(xb  + (size_t)rc * 32 + ko);
    short8v A1 = *reinterpret_cast<const short8v*>(t1b + (size_t)rc * 32 + ko);
    short8v A2 = *reinterpret_cast<const short8v*>(
        reinterpret_cast<const short*>(t2b) + (size_t)rc * 32 + ko);
    short8v A3;
#pragma unroll
    for (int j = 0; j < 8; ++j)   // Tx3 = 2*prop(Tx2) - Tx1
        A3[j] = f2bf(2.f * (acc0[j] + acc1[j]) - bf2f((unsigned short)A1[j]));

    const short8v* Pv = reinterpret_cast<const short8v*>(P);
    f32x4 acc[12];
#pragma unroll
    for (int nt = 0; nt < 12; ++nt) {
        const short8v* Pb = Pv + (size_t)nt * 4 * 64 + lane;
        f32x4 a = {0.f, 0.f, 0.f, 0.f};
        a = __builtin_amdgcn_mfma_f32_16x16x32_bf16(A0, Pb[0],   a, 0, 0, 0);
        a = __builtin_amdgcn_mfma_f32_16x16x32_bf16(A1, Pb[64],  a, 0, 0, 0);
        a = __builtin_amdgcn_mfma_f32_16x16x32_bf16(A2, Pb[128], a, 0, 0, 0);
        a = __builtin_amdgcn_mfma_f32_16x16x32_bf16(A3, Pb[192], a, 0, 0, 0);
        acc[nt] = a;
    }

    const int hq = lane & 15;
    const int ng = lane >> 4;
    const float lb = lin_b[0];
    float p[4] = {0.f, 0.f, 0.f, 0.f};
#pragma unroll
    for (int ht = 0; ht < 4; ++ht) {
        int h = ht * 16 + hq;
        float bI = bx[h] + bh[h] + bg[h];
        float bC = bx[128 + h] + bh[128 + h] + bg[128 + h];
        float bO = bx[192 + h] + bh[192 + h] + bg[192 + h];
        float w2 = wc[128 + h];
        float lw = lin_w[h];
#pragma unroll
        for (int r = 0; r < 4; ++r) {
            float I = sigf(acc[ht][r] + bI);
            float T = tanhf_fast(acc[4 + ht][r] + bC);
            float C = I * T;
            float O = sigf(acc[8 + ht][r] + bO + w2 * C);
            float H = O * tanhf_fast(C);
            p[r] = fmaf(H, lw, p[r]);
        }
    }
#pragma unroll
    for (int r = 0; r < 4; ++r) {
        float v = p[r];
        v += __shfl_xor(v, 1);
        v += __shfl_xor(v, 2);
        v += __shfl_xor(v, 4);
        v += __shfl_xor(v, 8);
        if (hq == 0) {
            int n = nb + ng * 4 + r;
            if (n < N) out[n] = v + lb;
        }
    }
}

extern "C" void kernel_launch(void* const* d_in, const int* in_sizes, int n_in,
                              void* d_out, int out_size, void* d_ws, size_t ws_size,
                              hipStream_t stream) {
    const float* x   = (const float*)d_in[0];
    const int*   ei  = (const int*)d_in[1];
    const float* ew  = (const float*)d_in[2];
    const float* Wx  = (const float*)d_in[3];
    const float* bx  = (const float*)d_in[4];
    // d_in[5] = Wh (unused: zero initial state)
    const float* bh  = (const float*)d_in[6];
    const float* wcp = (const float*)d_in[7];
    const float* bg  = (const float*)d_in[8];
    const float* lw  = (const float*)d_in[9];
    const float* lb  = (const float*)d_in[10];
    float* out = (float*)d_out;

    const int N  = in_sizes[0] / 32;
    const int nE = in_sizes[2];
    const int* src = ei;
    const int* dst = ei + nE;

    char* ws = (char*)d_ws;
    size_t off = 0;
    float* dinv    = (float*)(ws + off); off += (size_t)N * 4;
    int*   cnt     = (int*)(ws + off);   off += (size_t)N * 4;
    int*   rowptr  = (int*)(ws + off);   off += (size_t)N * 4;
    int*   partials= (int*)(ws + off);   off += 1024 * 4;
    int*   flag    = (int*)(ws + off);   off += 256;          // barrier counter
    short* P       = (short*)(ws + off); off += 12 * 4 * 64 * 8 * 2;
    int2*  entries = (int2*)(ws + off);  off += (size_t)nE * 8;
    float* degPart = (float*)(ws + off); off += (size_t)NCH * N * 4;  // aliased as offs
    unsigned short* cntPart = (unsigned short*)(ws + off); off += (size_t)NCH * N * 2;
    short* xbuf    = (short*)(ws + off); off += (size_t)N * 32 * 2;
    short* Tx1b    = (short*)(ws + off); off += (size_t)N * 32 * 2;
    short* Tx2b    = (short*)(ws + off); off += (size_t)N * 32 * 2;

    int* offs = (int*)degPart;  // degPart dead after k_scan_merged phase 1

    const int nRangeH = (N + RSH - 1) / RSH;
    const int nRangeF = (N + RSF - 1) / RSF;
    const int histB = nRangeH * NCH;
    const int n4 = N * 8;
    const int xbB = (12 * 4 * 64 + n4 + 1023) / 1024;
    const int nb2 = (N + NT * 2 - 1) / (NT * 2);   // 98 blocks (co-resident)

    hipMemsetAsync(flag, 0, 4, stream);
    k_front<<<histB + xbB, 1024, 0, stream>>>(src, dst, ew, degPart, cntPart,
                                              Wx, P, x, xbuf, nE, N, histB, n4);
    k_scan_merged<<<nb2, NT, 0, stream>>>(degPart, cntPart, dinv, cnt, rowptr,
                                          partials, flag, offs, N);
    k_fill2<<<nRangeF * NCH, 1024, 0, stream>>>(src, dst, ew, dinv, offs,
                                                entries, nE, N);

    const int gb = (N * 16 + NT - 1) / NT;
    k_gather_bf<<<gb, NT, 0, stream>>>((const unsigned short*)xbuf, nullptr,
                                       Tx1b, rowptr, cnt, entries, 1.f, N);
    k_gather_bf<<<gb, NT, 0, stream>>>((const unsigned short*)Tx1b,
                                       (const unsigned short*)xbuf,
                                       Tx2b, rowptr, cnt, entries, 2.f, N);

    const int fb = (N + 63) / 64;
    k_final_g3<<<fb, NT, 0, stream>>>(xbuf, Tx1b, (const unsigned short*)Tx2b, P,
                                      rowptr, cnt, entries, bx, bh, wcp, bg,
                                      lw, lb, out, N);
}